// Round 7
// baseline (152.148 us; speedup 1.0000x reference)
//
#include <hip/hip_runtime.h>

typedef __attribute__((ext_vector_type(8))) short bf16x8;
typedef __attribute__((ext_vector_type(4))) float f32x4;
typedef __attribute__((ext_vector_type(4))) unsigned short u16x4;
typedef __attribute__((ext_vector_type(8))) unsigned short u16x8;
typedef __attribute__((ext_vector_type(4))) unsigned int u32x4;

#define MFMA(a, b, c) __builtin_amdgcn_mfma_f32_16x16x32_bf16(a, b, c, 0, 0, 0)

static __device__ __forceinline__ unsigned short f2bf(float x) {
    union { float f; unsigned u; } v; v.f = x;
    unsigned r = v.u + 0x7fffu + ((v.u >> 16) & 1u);   // round-to-nearest-even
    return (unsigned short)(r >> 16);
}

// ---------------- Kernel 0: W [1024][64] f32 -> Wt [3][64][1024] bf16 ----------------
__global__ __launch_bounds__(256) void wtrans_k(
    const float* __restrict__ Wk, const float* __restrict__ Wq,
    const float* __restrict__ Wv, unsigned short* __restrict__ Wt)
{
    __shared__ float tl[64][65];
    const int w = blockIdx.x >> 4, kt = blockIdx.x & 15;
    const float* W = (w == 0) ? Wk : (w == 1) ? Wq : Wv;
    const int tid = threadIdx.x;
#pragma unroll
    for (int rep = 0; rep < 4; rep++) {
        int flat = rep * 256 + tid;
        int rr = flat >> 4, c4 = (flat & 15) * 4;
        f32x4 v = *(const f32x4*)(W + (kt * 64 + rr) * 64 + c4);
#pragma unroll
        for (int j = 0; j < 4; j++) tl[c4 + j][rr] = v[j];
    }
    __syncthreads();
#pragma unroll
    for (int rep = 0; rep < 2; rep++) {
        int flat = rep * 256 + tid;
        int n = flat >> 3, k8 = (flat & 7) * 8;
        u16x8 h;
#pragma unroll
        for (int j = 0; j < 8; j++) h[j] = f2bf(tl[n][k8 + j]);
        *(u16x8*)(Wt + w * 65536 + n * 1024 + kt * 64 + k8) = h;
    }
}

// ---------------- Kernel 1: QKV projection (unchanged) ----------------
__global__ __launch_bounds__(256) void qkv_k(
    const float* __restrict__ x, const unsigned short* __restrict__ Wt,
    unsigned short* __restrict__ Qb, unsigned short* __restrict__ Kb,
    unsigned short* __restrict__ Vt)
{
    __shared__ __align__(16) unsigned short xl[32][72];
    __shared__ __align__(16) unsigned short wl[192][72];
    const int tid = threadIdx.x;
    const int wid = tid >> 6, lane = tid & 63;
    const int lrow = lane & 15, g = lane >> 4;
    const int mbase = blockIdx.x * 32;
    const int msrow = (wid & 1) * 16;
    const int ntbase = (wid >> 1) * 6;

    f32x4 acc[6];
#pragma unroll
    for (int j = 0; j < 6; j++) acc[j] = (f32x4){0.f, 0.f, 0.f, 0.f};

    for (int kc = 0; kc < 1024; kc += 64) {
#pragma unroll
        for (int rep = 0; rep < 2; rep++) {
            int flat = rep * 256 + tid;
            int row = flat >> 4, c4 = (flat & 15) * 4;
            f32x4 v = *(const f32x4*)(x + (mbase + row) * 1024 + kc + c4);
            u16x4 h;
            h[0] = f2bf(v[0]); h[1] = f2bf(v[1]); h[2] = f2bf(v[2]); h[3] = f2bf(v[3]);
            *(u16x4*)&xl[row][c4] = h;
        }
#pragma unroll
        for (int rep = 0; rep < 6; rep++) {
            int flat = rep * 256 + tid;
            int n = flat >> 3, c = (flat & 7) * 8;
            *(u16x8*)&wl[n][c] = *(const u16x8*)(Wt + n * 1024 + kc + c);
        }
        __syncthreads();
#pragma unroll
        for (int ks = 0; ks < 2; ks++) {
            bf16x8 a = *(const bf16x8*)&xl[msrow + lrow][ks * 32 + g * 8];
#pragma unroll
            for (int j = 0; j < 6; j++) {
                bf16x8 b = *(const bf16x8*)&wl[(ntbase + j) * 16 + lrow][ks * 32 + g * 8];
                acc[j] = MFMA(a, b, acc[j]);
            }
        }
        __syncthreads();
    }

#pragma unroll
    for (int j = 0; j < 6; j++) {
        int nt = ntbase + j;
        int w = nt >> 2;
        int col = (nt & 3) * 16 + lrow;
        int r0 = mbase + msrow + g * 4;
        if (w == 2) {
            int b = r0 >> 11, t = r0 & 2047;
            u16x4 pv;
            pv[0] = f2bf(acc[j][0]); pv[1] = f2bf(acc[j][1]);
            pv[2] = f2bf(acc[j][2]); pv[3] = f2bf(acc[j][3]);
            *(u16x4*)(Vt + b * 131072 + col * 2048 + t) = pv;
        } else {
            unsigned short* dst = (w == 0) ? Kb : Qb;
#pragma unroll
            for (int i = 0; i < 4; i++)
                dst[(r0 + i) * 64 + col] = f2bf(acc[j][i]);
        }
    }
}

// ---------------- Kernel 2: attention — ROUND-6 BODY x4 (DIAGNOSTIC REPLICATION) ----------------
// Body is byte-for-byte round 6's algorithm; rep loop makes this dispatch ~4x longer so it
// surfaces in the rocprof top-5 with full counters. Each rep recomputes and rewrites the
// identical output (idempotent, deterministic).
__global__ __launch_bounds__(512) void attn_k(
    const unsigned short* __restrict__ Qb, const unsigned short* __restrict__ Kb,
    const unsigned short* __restrict__ Vt, float* __restrict__ out)
{
    __shared__ __align__(16) float po[8][16][68];
    __shared__ float ml[8][16];
    const int tid = threadIdx.x;
    const int wid = tid >> 6, lane = tid & 63;
    const int lrow = lane & 15, g = lane >> 4;
    const int batch = blockIdx.x >> 5;
    const int i = blockIdx.x & 31;

    const int nchL = i + 1;
    int wL = (nchL * 8 + 65) / 130; wL = wL < 1 ? 1 : (wL > 3 ? 3 : wL);
    const int wH = 4 - wL;

    int strip, rr, gs;
    if (wid < 2 * wL) {
        strip = (wid < wL) ? 2 * i : 2 * i + 1;
        rr = (wid < wL) ? wid : wid - wL;
        gs = wL;
    } else {
        int h = wid - 2 * wL;
        strip = (h < wH) ? 126 - 2 * i : 127 - 2 * i;
        rr = (h < wH) ? h : h - wH;
        gs = wH;
    }
    const int nch = (strip >> 1) + 1;
    const int q_local = strip * 16;
    const int qg = q_local + lrow;

    const unsigned short* Qrow = Qb + (batch * 2048 + q_local + lrow) * 64;
    bf16x8 qb0 = *(const bf16x8*)(Qrow + g * 8);
    bf16x8 qb1 = *(const bf16x8*)(Qrow + 32 + g * 8);

    const unsigned short* Kbase = Kb + batch * 2048 * 64;
    const unsigned short* Vbase = Vt + batch * 131072;
    const float C2 = 0.03125f * 1.44269504088896f;      // E^-0.5 * log2(e)
    const int step = gs * 32;

    for (int rep = 0; rep < 4; ++rep) {
        __syncthreads();                                 // protect po/ml across reps

        f32x4 o0 = {0.f,0.f,0.f,0.f}, o1 = o0, o2 = o0, o3 = o0;
        float lsum = 0.f;
        const unsigned short* kp = Kbase + (rr * 32 + lrow) * 64 + g * 8;
        const unsigned short* vp = Vbase + lrow * 2048 + rr * 32 + g * 8;

        bf16x8 k0 = {}, k1 = {}, k2 = {}, k3 = {};
        if (rr < nch) {
            k0 = *(const bf16x8*)(kp);
            k1 = *(const bf16x8*)(kp + 32);
            k2 = *(const bf16x8*)(kp + 1024);
            k3 = *(const bf16x8*)(kp + 1056);
        }

        for (int cc = rr; cc < nch; cc += gs) {
            const int kv0 = cc * 32;
            bf16x8 v0 = *(const bf16x8*)(vp);
            bf16x8 v1 = *(const bf16x8*)(vp + 32768);
            bf16x8 v2 = *(const bf16x8*)(vp + 65536);
            bf16x8 v3 = *(const bf16x8*)(vp + 98304);
            vp += step;
            const unsigned short* kpn = kp + ((cc + gs < nch) ? step * 64 : 0);
            bf16x8 nk0 = *(const bf16x8*)(kpn);
            bf16x8 nk1 = *(const bf16x8*)(kpn + 32);
            bf16x8 nk2 = *(const bf16x8*)(kpn + 1024);
            bf16x8 nk3 = *(const bf16x8*)(kpn + 1056);
            kp = kpn;

            f32x4 t0 = {0.f,0.f,0.f,0.f}, t1 = {0.f,0.f,0.f,0.f};
            t0 = MFMA(k0, qb0, t0);
            t0 = MFMA(k1, qb1, t0);
            t1 = MFMA(k2, qb0, t1);
            t1 = MFMA(k3, qb1, t1);

            const bool maskc = (cc == nch - 1);
            float e0v[4], e1v[4];
#pragma unroll
            for (int u = 0; u < 4; u++) {
                float a = t0[u] * C2;
                float b = t1[u] * C2;
                if (maskc) {
                    a = (kv0 + g * 4 + u > qg)      ? -INFINITY : a;
                    b = (kv0 + 16 + g * 4 + u > qg) ? -INFINITY : b;
                }
                e0v[u] = __builtin_exp2f(a);
                e1v[u] = __builtin_exp2f(b);
                lsum += e0v[u] + e1v[u];
            }

            unsigned a1, a2, b1, b2;
            asm("v_cvt_pk_bf16_f32 %0, %1, %2" : "=v"(a1) : "v"(e0v[0]), "v"(e0v[1]));
            asm("v_cvt_pk_bf16_f32 %0, %1, %2" : "=v"(a2) : "v"(e0v[2]), "v"(e0v[3]));
            asm("v_cvt_pk_bf16_f32 %0, %1, %2" : "=v"(b1) : "v"(e1v[0]), "v"(e1v[1]));
            asm("v_cvt_pk_bf16_f32 %0, %1, %2" : "=v"(b2) : "v"(e1v[2]), "v"(e1v[3]));
            asm("v_permlane32_swap_b32 %0, %1" : "+v"(a1), "+v"(b1));
            asm("v_permlane32_swap_b32 %0, %1" : "+v"(a2), "+v"(b2));
            int sa1 = __shfl_xor((int)a1, 16);
            int sa2 = __shfl_xor((int)a2, 16);
            int sb1 = __shfl_xor((int)b1, 16);
            int sb2 = __shfl_xor((int)b2, 16);
            u32x4 paw;
            const bool odd = (g & 1);
            paw[0] = odd ? (unsigned)sb1 : a1;
            paw[1] = odd ? (unsigned)sb2 : a2;
            paw[2] = odd ? b1 : (unsigned)sa1;
            paw[3] = odd ? b2 : (unsigned)sa2;
            bf16x8 pa = __builtin_bit_cast(bf16x8, paw);

            o0 = MFMA(pa, v0, o0);
            o1 = MFMA(pa, v1, o1);
            o2 = MFMA(pa, v2, o2);
            o3 = MFMA(pa, v3, o3);

            k0 = nk0; k1 = nk1; k2 = nk2; k3 = nk3;
        }

        lsum += __shfl_xor(lsum, 16);
        lsum += __shfl_xor(lsum, 32);

#pragma unroll
        for (int u = 0; u < 4; u++) {
            int row = g * 4 + u;
            po[wid][row][0 * 16 + lrow] = o0[u];
            po[wid][row][1 * 16 + lrow] = o1[u];
            po[wid][row][2 * 16 + lrow] = o2[u];
            po[wid][row][3 * 16 + lrow] = o3[u];
        }
        if (lane < 16) ml[wid][lane] = lsum;
        __syncthreads();

        {
            int row_id = tid >> 3;
            int cn = (tid & 7) * 8;
            int sidx = row_id >> 4;
            int row = row_id & 15;
            int w0, w1, strip_o;
            if (sidx == 0)      { w0 = 0;           w1 = wL;          strip_o = 2 * i; }
            else if (sidx == 1) { w0 = wL;          w1 = 2 * wL;      strip_o = 2 * i + 1; }
            else if (sidx == 2) { w0 = 2 * wL;      w1 = 2 * wL + wH; strip_o = 126 - 2 * i; }
            else                { w0 = 2 * wL + wH; w1 = 8;           strip_o = 127 - 2 * i; }
            float L = 0.f;
            f32x4 O0 = {0.f,0.f,0.f,0.f}, O1 = {0.f,0.f,0.f,0.f};
            for (int w = w0; w < w1; w++) {
                L += ml[w][row];
                O0 += *(const f32x4*)&po[w][row][cn];
                O1 += *(const f32x4*)&po[w][row][cn + 4];
            }
            float inv = 1.f / L;
            float* op = out + (batch * 2048 + strip_o * 16 + row) * 64 + cn;
            *(f32x4*)op       = O0 * inv;
            *(f32x4*)(op + 4) = O1 * inv;
        }
    }
}

extern "C" void kernel_launch(void* const* d_in, const int* in_sizes, int n_in,
                              void* d_out, int out_size, void* d_ws, size_t ws_size,
                              hipStream_t stream) {
    const float* x  = (const float*)d_in[0];
    const float* Wk = (const float*)d_in[1];
    const float* Wq = (const float*)d_in[2];
    const float* Wv = (const float*)d_in[3];
    float* out = (float*)d_out;

    unsigned short* Wt = (unsigned short*)d_ws;        // [192][1024] bf16
    unsigned short* Kb = Wt + 3 * 65536;               // [16384][64]
    unsigned short* Qb = Kb + 16384 * 64;              // [16384][64]
    unsigned short* Vt = Qb + 16384 * 64;              // [8][64][2048]

    wtrans_k<<<48, 256, 0, stream>>>(Wk, Wq, Wv, Wt);
    qkv_k<<<512, 256, 0, stream>>>(x, Wt, Qb, Kb, Vt);
    attn_k<<<256, 512, 0, stream>>>(Qb, Kb, Vt, out);
}

// Round 8
// 112.075 us; speedup vs baseline: 1.3575x; 1.3575x over previous
//
#include <hip/hip_runtime.h>

typedef __attribute__((ext_vector_type(8))) short bf16x8;
typedef __attribute__((ext_vector_type(4))) float f32x4;
typedef __attribute__((ext_vector_type(4))) unsigned short u16x4;
typedef __attribute__((ext_vector_type(8))) unsigned short u16x8;
typedef __attribute__((ext_vector_type(4))) unsigned int u32x4;

#define MFMA(a, b, c) __builtin_amdgcn_mfma_f32_16x16x32_bf16(a, b, c, 0, 0, 0)

static __device__ __forceinline__ unsigned short f2bf(float x) {
    union { float f; unsigned u; } v; v.f = x;
    unsigned r = v.u + 0x7fffu + ((v.u >> 16) & 1u);   // round-to-nearest-even
    return (unsigned short)(r >> 16);
}

// ---------------- Kernel 0: W [1024][64] f32 -> Wt [3][64][1024] bf16 ----------------
__global__ __launch_bounds__(256) void wtrans_k(
    const float* __restrict__ Wk, const float* __restrict__ Wq,
    const float* __restrict__ Wv, unsigned short* __restrict__ Wt)
{
    __shared__ float tl[64][65];
    const int w = blockIdx.x >> 4, kt = blockIdx.x & 15;
    const float* W = (w == 0) ? Wk : (w == 1) ? Wq : Wv;
    const int tid = threadIdx.x;
#pragma unroll
    for (int rep = 0; rep < 4; rep++) {
        int flat = rep * 256 + tid;
        int rr = flat >> 4, c4 = (flat & 15) * 4;
        f32x4 v = *(const f32x4*)(W + (kt * 64 + rr) * 64 + c4);
#pragma unroll
        for (int j = 0; j < 4; j++) tl[c4 + j][rr] = v[j];
    }
    __syncthreads();
#pragma unroll
    for (int rep = 0; rep < 2; rep++) {
        int flat = rep * 256 + tid;
        int n = flat >> 3, k8 = (flat & 7) * 8;
        u16x8 h;
#pragma unroll
        for (int j = 0; j < 8; j++) h[j] = f2bf(tl[n][k8 + j]);
        *(u16x8*)(Wt + w * 65536 + n * 1024 + kt * 64 + k8) = h;
    }
}

// ---------------- Kernel 1: QKV projection (staging now uses v_cvt_pk_bf16_f32) ----------------
__global__ __launch_bounds__(256) void qkv_k(
    const float* __restrict__ x, const unsigned short* __restrict__ Wt,
    unsigned short* __restrict__ Qb, unsigned short* __restrict__ Kb,
    unsigned short* __restrict__ Vt)
{
    __shared__ __align__(16) unsigned short xl[32][72];
    __shared__ __align__(16) unsigned short wl[192][72];
    const int tid = threadIdx.x;
    const int wid = tid >> 6, lane = tid & 63;
    const int lrow = lane & 15, g = lane >> 4;
    const int mbase = blockIdx.x * 32;
    const int msrow = (wid & 1) * 16;
    const int ntbase = (wid >> 1) * 6;

    f32x4 acc[6];
#pragma unroll
    for (int j = 0; j < 6; j++) acc[j] = (f32x4){0.f, 0.f, 0.f, 0.f};

    for (int kc = 0; kc < 1024; kc += 64) {
#pragma unroll
        for (int rep = 0; rep < 2; rep++) {
            int flat = rep * 256 + tid;
            int row = flat >> 4, c4 = (flat & 15) * 4;
            f32x4 v = *(const f32x4*)(x + (mbase + row) * 1024 + kc + c4);
            unsigned lo, hi;
            asm("v_cvt_pk_bf16_f32 %0, %1, %2" : "=v"(lo) : "v"(v[0]), "v"(v[1]));
            asm("v_cvt_pk_bf16_f32 %0, %1, %2" : "=v"(hi) : "v"(v[2]), "v"(v[3]));
            unsigned* dst = (unsigned*)&xl[row][c4];
            dst[0] = lo; dst[1] = hi;
        }
#pragma unroll
        for (int rep = 0; rep < 6; rep++) {
            int flat = rep * 256 + tid;
            int n = flat >> 3, c = (flat & 7) * 8;
            *(u16x8*)&wl[n][c] = *(const u16x8*)(Wt + n * 1024 + kc + c);
        }
        __syncthreads();
#pragma unroll
        for (int ks = 0; ks < 2; ks++) {
            bf16x8 a = *(const bf16x8*)&xl[msrow + lrow][ks * 32 + g * 8];
#pragma unroll
            for (int j = 0; j < 6; j++) {
                bf16x8 b = *(const bf16x8*)&wl[(ntbase + j) * 16 + lrow][ks * 32 + g * 8];
                acc[j] = MFMA(a, b, acc[j]);
            }
        }
        __syncthreads();
    }

#pragma unroll
    for (int j = 0; j < 6; j++) {
        int nt = ntbase + j;
        int w = nt >> 2;
        int col = (nt & 3) * 16 + lrow;
        int r0 = mbase + msrow + g * 4;
        if (w == 2) {
            int b = r0 >> 11, t = r0 & 2047;
            u16x4 pv;
            pv[0] = f2bf(acc[j][0]); pv[1] = f2bf(acc[j][1]);
            pv[2] = f2bf(acc[j][2]); pv[3] = f2bf(acc[j][3]);
            *(u16x4*)(Vt + b * 131072 + col * 2048 + t) = pv;
        } else {
            unsigned short* dst = (w == 0) ? Kb : Qb;
#pragma unroll
            for (int i = 0; i < 4; i++)
                dst[(r0 + i) * 64 + col] = f2bf(acc[j][i]);
        }
    }
}

// ---------------- Kernel 2: attention v8 — kv-split across blocks for occupancy ----------------
// 1024 blocks = batch(8) x pair(64) x half(2); 8 waves. Pair (p,127-p) = 65 chunks;
// half h takes chunks with parity h; waves split each strip's chunks round-robin.
// Fixed-max softmax => partials (o,l) are plain-additive; comb_k merges the 2 halves.
__global__ __launch_bounds__(512, 8) void attn_k(
    const unsigned short* __restrict__ Qb, const unsigned short* __restrict__ Kb,
    const unsigned short* __restrict__ Vt, float* __restrict__ pO,
    float* __restrict__ pL)
{
    __shared__ __align__(16) float po[8][16][68];
    __shared__ float ml[8][16];
    const int tid = threadIdx.x;
    const int wid = tid >> 6, lane = tid & 63;
    const int lrow = lane & 15, g = lane >> 4;
    const int bid = blockIdx.x;
    const int batch = bid >> 7;
    const int p = (bid >> 1) & 63;
    const int h = bid & 1;

    const int sA = p, sB = 127 - p;
    const int nchA = (sA >> 1) + 1;                     // nchA + nchB == 65
    int wA = (nchA * 8 + 32) / 65;
    wA = wA < 1 ? 1 : (wA > 7 ? 7 : wA);

    int strip, rr, gs;
    if (wid < wA) { strip = sA; rr = wid;      gs = wA; }
    else          { strip = sB; rr = wid - wA; gs = 8 - wA; }
    const int nch = (strip >> 1) + 1;
    const int q_local = strip * 16;
    const int qg = q_local + lrow;
    const int first_cc = 2 * rr + h;                    // this wave's first chunk
    const int cstep = 2 * gs;                           // chunk stride

    const unsigned short* Qrow = Qb + (batch * 2048 + q_local + lrow) * 64;
    bf16x8 qb0 = *(const bf16x8*)(Qrow + g * 8);
    bf16x8 qb1 = *(const bf16x8*)(Qrow + 32 + g * 8);

    const unsigned short* Kbase = Kb + batch * 2048 * 64;
    const unsigned short* Vbase = Vt + batch * 131072;

    f32x4 o0 = {0.f,0.f,0.f,0.f}, o1 = o0, o2 = o0, o3 = o0;
    float lsum = 0.f;
    const float C2 = 0.03125f * 1.44269504088896f;      // E^-0.5 * log2(e)

    const unsigned short* kp = Kbase + (first_cc * 32 + lrow) * 64 + g * 8;
    const unsigned short* vp = Vbase + lrow * 2048 + first_cc * 32 + g * 8;

    bf16x8 k0 = {}, k1 = {}, k2 = {}, k3 = {};
    if (first_cc < nch) {
        k0 = *(const bf16x8*)(kp);
        k1 = *(const bf16x8*)(kp + 32);
        k2 = *(const bf16x8*)(kp + 1024);
        k3 = *(const bf16x8*)(kp + 1056);
    }

    for (int cc = first_cc; cc < nch; cc += cstep) {
        const int kv0 = cc * 32;
        bf16x8 v0 = *(const bf16x8*)(vp);
        bf16x8 v1 = *(const bf16x8*)(vp + 32768);
        bf16x8 v2 = *(const bf16x8*)(vp + 65536);
        bf16x8 v3 = *(const bf16x8*)(vp + 98304);
        vp += cstep * 32;
        const unsigned short* kpn = kp + ((cc + cstep < nch) ? cstep * 32 * 64 : 0);
        bf16x8 nk0 = *(const bf16x8*)(kpn);
        bf16x8 nk1 = *(const bf16x8*)(kpn + 32);
        bf16x8 nk2 = *(const bf16x8*)(kpn + 1024);
        bf16x8 nk3 = *(const bf16x8*)(kpn + 1056);
        kp = kpn;

        f32x4 t0 = {0.f,0.f,0.f,0.f}, t1 = {0.f,0.f,0.f,0.f};
        t0 = MFMA(k0, qb0, t0);
        t0 = MFMA(k1, qb1, t0);
        t1 = MFMA(k2, qb0, t1);
        t1 = MFMA(k3, qb1, t1);

        const bool maskc = (cc == nch - 1);             // diagonal chunk only
        float e0v[4], e1v[4];
#pragma unroll
        for (int u = 0; u < 4; u++) {
            float a = t0[u] * C2;
            float b = t1[u] * C2;
            if (maskc) {
                a = (kv0 + g * 4 + u > qg)      ? -INFINITY : a;
                b = (kv0 + 16 + g * 4 + u > qg) ? -INFINITY : b;
            }
            e0v[u] = __builtin_exp2f(a);
            e1v[u] = __builtin_exp2f(b);
            lsum += e0v[u] + e1v[u];
        }

        unsigned a1, a2, b1, b2;
        asm("v_cvt_pk_bf16_f32 %0, %1, %2" : "=v"(a1) : "v"(e0v[0]), "v"(e0v[1]));
        asm("v_cvt_pk_bf16_f32 %0, %1, %2" : "=v"(a2) : "v"(e0v[2]), "v"(e0v[3]));
        asm("v_cvt_pk_bf16_f32 %0, %1, %2" : "=v"(b1) : "v"(e1v[0]), "v"(e1v[1]));
        asm("v_cvt_pk_bf16_f32 %0, %1, %2" : "=v"(b2) : "v"(e1v[2]), "v"(e1v[3]));
        asm("v_permlane32_swap_b32 %0, %1" : "+v"(a1), "+v"(b1));
        asm("v_permlane32_swap_b32 %0, %1" : "+v"(a2), "+v"(b2));
        int sa1 = __shfl_xor((int)a1, 16);
        int sa2 = __shfl_xor((int)a2, 16);
        int sb1 = __shfl_xor((int)b1, 16);
        int sb2 = __shfl_xor((int)b2, 16);
        u32x4 paw;
        const bool odd = (g & 1);
        paw[0] = odd ? (unsigned)sb1 : a1;
        paw[1] = odd ? (unsigned)sb2 : a2;
        paw[2] = odd ? b1 : (unsigned)sa1;
        paw[3] = odd ? b2 : (unsigned)sa2;
        bf16x8 pa = __builtin_bit_cast(bf16x8, paw);

        o0 = MFMA(pa, v0, o0);
        o1 = MFMA(pa, v1, o1);
        o2 = MFMA(pa, v2, o2);
        o3 = MFMA(pa, v3, o3);

        k0 = nk0; k1 = nk1; k2 = nk2; k3 = nk3;
    }

    lsum += __shfl_xor(lsum, 16);
    lsum += __shfl_xor(lsum, 32);

#pragma unroll
    for (int u = 0; u < 4; u++) {
        int row = g * 4 + u;
        po[wid][row][0 * 16 + lrow] = o0[u];
        po[wid][row][1 * 16 + lrow] = o1[u];
        po[wid][row][2 * 16 + lrow] = o2[u];
        po[wid][row][3 * 16 + lrow] = o3[u];
    }
    if (lane < 16) ml[wid][lane] = lsum;
    __syncthreads();

    // in-block reduce over waves -> per-half partial (o-sum, l-sum), no division
    {
        int row_id = tid >> 4;            // 0..31 (2 strips x 16 rows)
        int cn = (tid & 15) * 4;
        int sidx = row_id >> 4;
        int row = row_id & 15;
        int w0 = sidx ? wA : 0;
        int w1 = sidx ? 8 : wA;
        int strip_o = sidx ? sB : sA;
        float L = 0.f;
        f32x4 O = {0.f,0.f,0.f,0.f};
        for (int w = w0; w < w1; w++) {
            L += ml[w][row];
            O += *(const f32x4*)&po[w][row][cn];
        }
        int gr = batch * 2048 + strip_o * 16 + row;
        *(f32x4*)(pO + (h * 16384 + gr) * 64 + cn) = O;
        if (cn == 0) pL[h * 16384 + gr] = L;
    }
}

// ---------------- Kernel 3: merge the two kv-half partials ----------------
__global__ __launch_bounds__(256) void comb_k(
    const float* __restrict__ pO, const float* __restrict__ pL,
    float* __restrict__ out)
{
    int id = blockIdx.x * 256 + threadIdx.x;   // 65536 = 16384 rows x 4 quarters
    int row = id >> 2, q = (id & 3) * 16;
    float inv = 1.f / (pL[row] + pL[16384 + row]);
    const float* p0 = pO + row * 64 + q;
    const float* p1 = pO + (16384 + row) * 64 + q;
    float* op = out + row * 64 + q;
#pragma unroll
    for (int j = 0; j < 4; j++) {
        f32x4 a = *(const f32x4*)(p0 + 4 * j);
        f32x4 b = *(const f32x4*)(p1 + 4 * j);
        *(f32x4*)(op + 4 * j) = (a + b) * inv;
    }
}

extern "C" void kernel_launch(void* const* d_in, const int* in_sizes, int n_in,
                              void* d_out, int out_size, void* d_ws, size_t ws_size,
                              hipStream_t stream) {
    const float* x  = (const float*)d_in[0];
    const float* Wk = (const float*)d_in[1];
    const float* Wq = (const float*)d_in[2];
    const float* Wv = (const float*)d_in[3];
    float* out = (float*)d_out;

    unsigned short* Wt = (unsigned short*)d_ws;        // [192][1024] bf16
    unsigned short* Kb = Wt + 3 * 65536;               // [16384][64]
    unsigned short* Qb = Kb + 16384 * 64;              // [16384][64]
    unsigned short* Vt = Qb + 16384 * 64;              // [8][64][2048]
    float* pO = (float*)(Vt + 131072 * 8);             // [2][16384][64] f32 partial o
    float* pL = pO + 2 * 16384 * 64;                   // [2][16384] f32 partial l

    wtrans_k<<<48, 256, 0, stream>>>(Wk, Wq, Wv, Wt);
    qkv_k<<<512, 256, 0, stream>>>(x, Wt, Qb, Kb, Vt);
    attn_k<<<1024, 512, 0, stream>>>(Qb, Kb, Vt, pO, pL);
    comb_k<<<256, 256, 0, stream>>>(pO, pL, out);
}

// Round 9
// 70.671 us; speedup vs baseline: 2.1529x; 1.5859x over previous
//
#include <hip/hip_runtime.h>

typedef __attribute__((ext_vector_type(8))) short bf16x8;
typedef __attribute__((ext_vector_type(4))) float f32x4;
typedef __attribute__((ext_vector_type(4))) unsigned short u16x4;
typedef __attribute__((ext_vector_type(8))) unsigned short u16x8;
typedef __attribute__((ext_vector_type(4))) unsigned int u32x4;

#define MFMA(a, b, c) __builtin_amdgcn_mfma_f32_16x16x32_bf16(a, b, c, 0, 0, 0)

static __device__ __forceinline__ unsigned short f2bf(float x) {
    union { float f; unsigned u; } v; v.f = x;
    unsigned r = v.u + 0x7fffu + ((v.u >> 16) & 1u);   // round-to-nearest-even
    return (unsigned short)(r >> 16);
}

// ---------------- Kernel 0: W [1024][64] f32 -> Wt [3][64][1024] bf16 ----------------
__global__ __launch_bounds__(256) void wtrans_k(
    const float* __restrict__ Wk, const float* __restrict__ Wq,
    const float* __restrict__ Wv, unsigned short* __restrict__ Wt)
{
    __shared__ float tl[64][65];
    const int w = blockIdx.x >> 4, kt = blockIdx.x & 15;
    const float* W = (w == 0) ? Wk : (w == 1) ? Wq : Wv;
    const int tid = threadIdx.x;
#pragma unroll
    for (int rep = 0; rep < 4; rep++) {
        int flat = rep * 256 + tid;
        int rr = flat >> 4, c4 = (flat & 15) * 4;
        f32x4 v = *(const f32x4*)(W + (kt * 64 + rr) * 64 + c4);
#pragma unroll
        for (int j = 0; j < 4; j++) tl[c4 + j][rr] = v[j];
    }
    __syncthreads();
#pragma unroll
    for (int rep = 0; rep < 2; rep++) {
        int flat = rep * 256 + tid;
        int n = flat >> 3, k8 = (flat & 7) * 8;
        u16x8 h;
#pragma unroll
        for (int j = 0; j < 8; j++) h[j] = f2bf(tl[n][k8 + j]);
        *(u16x8*)(Wt + w * 65536 + n * 1024 + kt * 64 + k8) = h;
    }
}

// ---------------- Kernel 1: QKV projection ----------------
__global__ __launch_bounds__(256) void qkv_k(
    const float* __restrict__ x, const unsigned short* __restrict__ Wt,
    unsigned short* __restrict__ Qb, unsigned short* __restrict__ Kb,
    unsigned short* __restrict__ Vt)
{
    __shared__ __align__(16) unsigned short xl[32][72];
    __shared__ __align__(16) unsigned short wl[192][72];
    const int tid = threadIdx.x;
    const int wid = tid >> 6, lane = tid & 63;
    const int lrow = lane & 15, g = lane >> 4;
    const int mbase = blockIdx.x * 32;
    const int msrow = (wid & 1) * 16;
    const int ntbase = (wid >> 1) * 6;

    f32x4 acc[6];
#pragma unroll
    for (int j = 0; j < 6; j++) acc[j] = (f32x4){0.f, 0.f, 0.f, 0.f};

    for (int kc = 0; kc < 1024; kc += 64) {
#pragma unroll
        for (int rep = 0; rep < 2; rep++) {
            int flat = rep * 256 + tid;
            int row = flat >> 4, c4 = (flat & 15) * 4;
            f32x4 v = *(const f32x4*)(x + (mbase + row) * 1024 + kc + c4);
            unsigned lo, hi;
            asm("v_cvt_pk_bf16_f32 %0, %1, %2" : "=v"(lo) : "v"(v[0]), "v"(v[1]));
            asm("v_cvt_pk_bf16_f32 %0, %1, %2" : "=v"(hi) : "v"(v[2]), "v"(v[3]));
            unsigned* dst = (unsigned*)&xl[row][c4];
            dst[0] = lo; dst[1] = hi;
        }
#pragma unroll
        for (int rep = 0; rep < 6; rep++) {
            int flat = rep * 256 + tid;
            int n = flat >> 3, c = (flat & 7) * 8;
            *(u16x8*)&wl[n][c] = *(const u16x8*)(Wt + n * 1024 + kc + c);
        }
        __syncthreads();
#pragma unroll
        for (int ks = 0; ks < 2; ks++) {
            bf16x8 a = *(const bf16x8*)&xl[msrow + lrow][ks * 32 + g * 8];
#pragma unroll
            for (int j = 0; j < 6; j++) {
                bf16x8 b = *(const bf16x8*)&wl[(ntbase + j) * 16 + lrow][ks * 32 + g * 8];
                acc[j] = MFMA(a, b, acc[j]);
            }
        }
        __syncthreads();
    }

#pragma unroll
    for (int j = 0; j < 6; j++) {
        int nt = ntbase + j;
        int w = nt >> 2;
        int col = (nt & 3) * 16 + lrow;
        int r0 = mbase + msrow + g * 4;
        if (w == 2) {
            int b = r0 >> 11, t = r0 & 2047;
            u16x4 pv;
            pv[0] = f2bf(acc[j][0]); pv[1] = f2bf(acc[j][1]);
            pv[2] = f2bf(acc[j][2]); pv[3] = f2bf(acc[j][3]);
            *(u16x4*)(Vt + b * 131072 + col * 2048 + t) = pv;
        } else {
            unsigned short* dst = (w == 0) ? Kb : Qb;
#pragma unroll
            for (int i = 0; i < 4; i++)
                dst[(r0 + i) * 64 + col] = f2bf(acc[j][i]);
        }
    }
}

// ---------------- Kernel 2: attention v9 — round-8 structure, NO min-waves bound ----------------
// (round 8's __launch_bounds__(512,8) capped regs at 64 -> spill; natural alloc ~60 VGPR
// already permits 8 waves/SIMD, LDS 35KB permits 4 blocks/CU.)
__global__ __launch_bounds__(512) void attn_k(
    const unsigned short* __restrict__ Qb, const unsigned short* __restrict__ Kb,
    const unsigned short* __restrict__ Vt, float* __restrict__ pO,
    float* __restrict__ pL)
{
    __shared__ __align__(16) float po[8][16][68];
    __shared__ float ml[8][16];
    const int tid = threadIdx.x;
    const int wid = tid >> 6, lane = tid & 63;
    const int lrow = lane & 15, g = lane >> 4;
    const int bid = blockIdx.x;
    const int batch = bid >> 7;
    const int p = (bid >> 1) & 63;
    const int h = bid & 1;

    const int sA = p, sB = 127 - p;
    const int nchA = (sA >> 1) + 1;                     // nchA + nchB == 65
    int wA = (nchA * 8 + 32) / 65;
    wA = wA < 1 ? 1 : (wA > 7 ? 7 : wA);

    int strip, rr, gs;
    if (wid < wA) { strip = sA; rr = wid;      gs = wA; }
    else          { strip = sB; rr = wid - wA; gs = 8 - wA; }
    const int nch = (strip >> 1) + 1;
    const int q_local = strip * 16;
    const int qg = q_local + lrow;
    const int first_cc = 2 * rr + h;                    // this wave's first chunk
    const int cstep = 2 * gs;                           // chunk stride

    const unsigned short* Qrow = Qb + (batch * 2048 + q_local + lrow) * 64;
    bf16x8 qb0 = *(const bf16x8*)(Qrow + g * 8);
    bf16x8 qb1 = *(const bf16x8*)(Qrow + 32 + g * 8);

    const unsigned short* Kbase = Kb + batch * 2048 * 64;
    const unsigned short* Vbase = Vt + batch * 131072;

    f32x4 o0 = {0.f,0.f,0.f,0.f}, o1 = o0, o2 = o0, o3 = o0;
    float lsum = 0.f;
    const float C2 = 0.03125f * 1.44269504088896f;      // E^-0.5 * log2(e)

    const unsigned short* kp = Kbase + (first_cc * 32 + lrow) * 64 + g * 8;
    const unsigned short* vp = Vbase + lrow * 2048 + first_cc * 32 + g * 8;

    bf16x8 k0 = {}, k1 = {}, k2 = {}, k3 = {};
    if (first_cc < nch) {
        k0 = *(const bf16x8*)(kp);
        k1 = *(const bf16x8*)(kp + 32);
        k2 = *(const bf16x8*)(kp + 1024);
        k3 = *(const bf16x8*)(kp + 1056);
    }

    for (int cc = first_cc; cc < nch; cc += cstep) {
        const int kv0 = cc * 32;
        bf16x8 v0 = *(const bf16x8*)(vp);
        bf16x8 v1 = *(const bf16x8*)(vp + 32768);
        bf16x8 v2 = *(const bf16x8*)(vp + 65536);
        bf16x8 v3 = *(const bf16x8*)(vp + 98304);
        vp += cstep * 32;
        const unsigned short* kpn = kp + ((cc + cstep < nch) ? cstep * 32 * 64 : 0);
        bf16x8 nk0 = *(const bf16x8*)(kpn);
        bf16x8 nk1 = *(const bf16x8*)(kpn + 32);
        bf16x8 nk2 = *(const bf16x8*)(kpn + 1024);
        bf16x8 nk3 = *(const bf16x8*)(kpn + 1056);
        kp = kpn;

        f32x4 t0 = {0.f,0.f,0.f,0.f}, t1 = {0.f,0.f,0.f,0.f};
        t0 = MFMA(k0, qb0, t0);
        t0 = MFMA(k1, qb1, t0);
        t1 = MFMA(k2, qb0, t1);
        t1 = MFMA(k3, qb1, t1);

        const bool maskc = (cc == nch - 1);             // diagonal chunk only
        float e0v[4], e1v[4];
#pragma unroll
        for (int u = 0; u < 4; u++) {
            float a = t0[u] * C2;
            float b = t1[u] * C2;
            if (maskc) {
                a = (kv0 + g * 4 + u > qg)      ? -INFINITY : a;
                b = (kv0 + 16 + g * 4 + u > qg) ? -INFINITY : b;
            }
            e0v[u] = __builtin_exp2f(a);
            e1v[u] = __builtin_exp2f(b);
            lsum += e0v[u] + e1v[u];
        }

        unsigned a1, a2, b1, b2;
        asm("v_cvt_pk_bf16_f32 %0, %1, %2" : "=v"(a1) : "v"(e0v[0]), "v"(e0v[1]));
        asm("v_cvt_pk_bf16_f32 %0, %1, %2" : "=v"(a2) : "v"(e0v[2]), "v"(e0v[3]));
        asm("v_cvt_pk_bf16_f32 %0, %1, %2" : "=v"(b1) : "v"(e1v[0]), "v"(e1v[1]));
        asm("v_cvt_pk_bf16_f32 %0, %1, %2" : "=v"(b2) : "v"(e1v[2]), "v"(e1v[3]));
        asm("v_permlane32_swap_b32 %0, %1" : "+v"(a1), "+v"(b1));
        asm("v_permlane32_swap_b32 %0, %1" : "+v"(a2), "+v"(b2));
        int sa1 = __shfl_xor((int)a1, 16);
        int sa2 = __shfl_xor((int)a2, 16);
        int sb1 = __shfl_xor((int)b1, 16);
        int sb2 = __shfl_xor((int)b2, 16);
        u32x4 paw;
        const bool odd = (g & 1);
        paw[0] = odd ? (unsigned)sb1 : a1;
        paw[1] = odd ? (unsigned)sb2 : a2;
        paw[2] = odd ? b1 : (unsigned)sa1;
        paw[3] = odd ? b2 : (unsigned)sa2;
        bf16x8 pa = __builtin_bit_cast(bf16x8, paw);

        o0 = MFMA(pa, v0, o0);
        o1 = MFMA(pa, v1, o1);
        o2 = MFMA(pa, v2, o2);
        o3 = MFMA(pa, v3, o3);

        k0 = nk0; k1 = nk1; k2 = nk2; k3 = nk3;
    }

    lsum += __shfl_xor(lsum, 16);
    lsum += __shfl_xor(lsum, 32);

#pragma unroll
    for (int u = 0; u < 4; u++) {
        int row = g * 4 + u;
        po[wid][row][0 * 16 + lrow] = o0[u];
        po[wid][row][1 * 16 + lrow] = o1[u];
        po[wid][row][2 * 16 + lrow] = o2[u];
        po[wid][row][3 * 16 + lrow] = o3[u];
    }
    if (lane < 16) ml[wid][lane] = lsum;
    __syncthreads();

    // in-block reduce over waves -> per-half partial (o-sum, l-sum), no division
    {
        int row_id = tid >> 4;            // 0..31 (2 strips x 16 rows)
        int cn = (tid & 15) * 4;
        int sidx = row_id >> 4;
        int row = row_id & 15;
        int w0 = sidx ? wA : 0;
        int w1 = sidx ? 8 : wA;
        int strip_o = sidx ? sB : sA;
        float L = 0.f;
        f32x4 O = {0.f,0.f,0.f,0.f};
        for (int w = w0; w < w1; w++) {
            L += ml[w][row];
            O += *(const f32x4*)&po[w][row][cn];
        }
        int gr = batch * 2048 + strip_o * 16 + row;
        *(f32x4*)(pO + (h * 16384 + gr) * 64 + cn) = O;
        if (cn == 0) pL[h * 16384 + gr] = L;
    }
}

// ---------------- Kernel 3: merge the two kv-half partials ----------------
__global__ __launch_bounds__(256) void comb_k(
    const float* __restrict__ pO, const float* __restrict__ pL,
    float* __restrict__ out)
{
    int id = blockIdx.x * 256 + threadIdx.x;   // 65536 = 16384 rows x 4 quarters
    int row = id >> 2, q = (id & 3) * 16;
    float inv = 1.f / (pL[row] + pL[16384 + row]);
    const float* p0 = pO + row * 64 + q;
    const float* p1 = pO + (16384 + row) * 64 + q;
    float* op = out + row * 64 + q;
#pragma unroll
    for (int j = 0; j < 4; j++) {
        f32x4 a = *(const f32x4*)(p0 + 4 * j);
        f32x4 b = *(const f32x4*)(p1 + 4 * j);
        *(f32x4*)(op + 4 * j) = (a + b) * inv;
    }
}

extern "C" void kernel_launch(void* const* d_in, const int* in_sizes, int n_in,
                              void* d_out, int out_size, void* d_ws, size_t ws_size,
                              hipStream_t stream) {
    const float* x  = (const float*)d_in[0];
    const float* Wk = (const float*)d_in[1];
    const float* Wq = (const float*)d_in[2];
    const float* Wv = (const float*)d_in[3];
    float* out = (float*)d_out;

    unsigned short* Wt = (unsigned short*)d_ws;        // [192][1024] bf16
    unsigned short* Kb = Wt + 3 * 65536;               // [16384][64]
    unsigned short* Qb = Kb + 16384 * 64;              // [16384][64]
    unsigned short* Vt = Qb + 16384 * 64;              // [8][64][2048]
    float* pO = (float*)(Vt + 131072 * 8);             // [2][16384][64] f32 partial o
    float* pL = pO + 2 * 16384 * 64;                   // [2][16384] f32 partial l

    wtrans_k<<<48, 256, 0, stream>>>(Wk, Wq, Wv, Wt);
    qkv_k<<<512, 256, 0, stream>>>(x, Wt, Qb, Kb, Vt);
    attn_k<<<1024, 512, 0, stream>>>(Qb, Kb, Vt, pO, pL);
    comb_k<<<256, 256, 0, stream>>>(pO, pL, out);
}

// Round 10
// 53.713 us; speedup vs baseline: 2.8326x; 1.3157x over previous
//
#include <hip/hip_runtime.h>

typedef __attribute__((ext_vector_type(8))) short bf16x8;
typedef __attribute__((ext_vector_type(4))) float f32x4;
typedef __attribute__((ext_vector_type(4))) unsigned short u16x4;
typedef __attribute__((ext_vector_type(8))) unsigned short u16x8;
typedef __attribute__((ext_vector_type(4))) unsigned int u32x4;

#define MFMA(a, b, c) __builtin_amdgcn_mfma_f32_16x16x32_bf16(a, b, c, 0, 0, 0)

static __device__ __forceinline__ unsigned short f2bf(float x) {
    union { float f; unsigned u; } v; v.f = x;
    unsigned r = v.u + 0x7fffu + ((v.u >> 16) & 1u);   // round-to-nearest-even
    return (unsigned short)(r >> 16);
}

// P-fragment pack: e{a}=P[kv g*4+u][q=lrow] (low 16 kv), e{b}= +16 kv.
// Returns A-frag bf16x8 covering the 32-kv window (verified rounds 4-9).
static __device__ __forceinline__ bf16x8 pack_pa(
    float ea0, float ea1, float ea2, float ea3,
    float eb0, float eb1, float eb2, float eb3, bool odd)
{
    unsigned a1, a2, b1, b2;
    asm("v_cvt_pk_bf16_f32 %0, %1, %2" : "=v"(a1) : "v"(ea0), "v"(ea1));
    asm("v_cvt_pk_bf16_f32 %0, %1, %2" : "=v"(a2) : "v"(ea2), "v"(ea3));
    asm("v_cvt_pk_bf16_f32 %0, %1, %2" : "=v"(b1) : "v"(eb0), "v"(eb1));
    asm("v_cvt_pk_bf16_f32 %0, %1, %2" : "=v"(b2) : "v"(eb2), "v"(eb3));
    asm("v_permlane32_swap_b32 %0, %1" : "+v"(a1), "+v"(b1));
    asm("v_permlane32_swap_b32 %0, %1" : "+v"(a2), "+v"(b2));
    int sa1 = __shfl_xor((int)a1, 16);
    int sa2 = __shfl_xor((int)a2, 16);
    int sb1 = __shfl_xor((int)b1, 16);
    int sb2 = __shfl_xor((int)b2, 16);
    u32x4 paw;
    paw[0] = odd ? (unsigned)sb1 : a1;
    paw[1] = odd ? (unsigned)sb2 : a2;
    paw[2] = odd ? b1 : (unsigned)sa1;
    paw[3] = odd ? b2 : (unsigned)sa2;
    return __builtin_bit_cast(bf16x8, paw);
}

// ---------------- Kernel 0: W [1024][64] f32 -> Wt [3][64][1024] bf16 ----------------
__global__ __launch_bounds__(256) void wtrans_k(
    const float* __restrict__ Wk, const float* __restrict__ Wq,
    const float* __restrict__ Wv, unsigned short* __restrict__ Wt)
{
    __shared__ float tl[64][65];
    const int w = blockIdx.x >> 4, kt = blockIdx.x & 15;
    const float* W = (w == 0) ? Wk : (w == 1) ? Wq : Wv;
    const int tid = threadIdx.x;
#pragma unroll
    for (int rep = 0; rep < 4; rep++) {
        int flat = rep * 256 + tid;
        int rr = flat >> 4, c4 = (flat & 15) * 4;
        f32x4 v = *(const f32x4*)(W + (kt * 64 + rr) * 64 + c4);
#pragma unroll
        for (int jj = 0; jj < 4; jj++) tl[c4 + jj][rr] = v[jj];
    }
    __syncthreads();
#pragma unroll
    for (int rep = 0; rep < 2; rep++) {
        int flat = rep * 256 + tid;
        int n = flat >> 3, k8 = (flat & 7) * 8;
        u16x8 h;
#pragma unroll
        for (int jj = 0; jj < 8; jj++) h[jj] = f2bf(tl[n][k8 + jj]);
        *(u16x8*)(Wt + w * 65536 + n * 1024 + kt * 64 + k8) = h;
    }
}

// ---------------- Kernel 1: QKV projection (unchanged) ----------------
__global__ __launch_bounds__(256) void qkv_k(
    const float* __restrict__ x, const unsigned short* __restrict__ Wt,
    unsigned short* __restrict__ Qb, unsigned short* __restrict__ Kb,
    unsigned short* __restrict__ Vt)
{
    __shared__ __align__(16) unsigned short xl[32][72];
    __shared__ __align__(16) unsigned short wl[192][72];
    const int tid = threadIdx.x;
    const int wid = tid >> 6, lane = tid & 63;
    const int lrow = lane & 15, g = lane >> 4;
    const int mbase = blockIdx.x * 32;
    const int msrow = (wid & 1) * 16;
    const int ntbase = (wid >> 1) * 6;

    f32x4 acc[6];
#pragma unroll
    for (int jj = 0; jj < 6; jj++) acc[jj] = (f32x4){0.f, 0.f, 0.f, 0.f};

    for (int kc = 0; kc < 1024; kc += 64) {
#pragma unroll
        for (int rep = 0; rep < 2; rep++) {
            int flat = rep * 256 + tid;
            int row = flat >> 4, c4 = (flat & 15) * 4;
            f32x4 v = *(const f32x4*)(x + (mbase + row) * 1024 + kc + c4);
            unsigned lo, hi;
            asm("v_cvt_pk_bf16_f32 %0, %1, %2" : "=v"(lo) : "v"(v[0]), "v"(v[1]));
            asm("v_cvt_pk_bf16_f32 %0, %1, %2" : "=v"(hi) : "v"(v[2]), "v"(v[3]));
            unsigned* dst = (unsigned*)&xl[row][c4];
            dst[0] = lo; dst[1] = hi;
        }
#pragma unroll
        for (int rep = 0; rep < 6; rep++) {
            int flat = rep * 256 + tid;
            int n = flat >> 3, c = (flat & 7) * 8;
            *(u16x8*)&wl[n][c] = *(const u16x8*)(Wt + n * 1024 + kc + c);
        }
        __syncthreads();
#pragma unroll
        for (int ks = 0; ks < 2; ks++) {
            bf16x8 a = *(const bf16x8*)&xl[msrow + lrow][ks * 32 + g * 8];
#pragma unroll
            for (int jj = 0; jj < 6; jj++) {
                bf16x8 b = *(const bf16x8*)&wl[(ntbase + jj) * 16 + lrow][ks * 32 + g * 8];
                acc[jj] = MFMA(a, b, acc[jj]);
            }
        }
        __syncthreads();
    }

#pragma unroll
    for (int jj = 0; jj < 6; jj++) {
        int nt = ntbase + jj;
        int w = nt >> 2;
        int col = (nt & 3) * 16 + lrow;
        int r0 = mbase + msrow + g * 4;
        if (w == 2) {
            int b = r0 >> 11, t = r0 & 2047;
            u16x4 pv;
            pv[0] = f2bf(acc[jj][0]); pv[1] = f2bf(acc[jj][1]);
            pv[2] = f2bf(acc[jj][2]); pv[3] = f2bf(acc[jj][3]);
            *(u16x4*)(Vt + b * 131072 + col * 2048 + t) = pv;
        } else {
            unsigned short* dst = (w == 0) ? Kb : Qb;
#pragma unroll
            for (int i = 0; i < 4; i++)
                dst[(r0 + i) * 64 + col] = f2bf(acc[jj][i]);
        }
    }
}

// ---------------- Kernel 2: attention v10 — LDS-staged chunks, shared across waves ----------------
// 512 blocks = batch(8) x band-pair(16) x kv-quarter(4); 4 waves x 16 q-rows = band of 64 q.
// Per chunk (64 kv): stage K[64][64] + V^T[64][64] to LDS (coalesced, XOR-swizzled granules,
// double-buffered); all 4 waves consume. This cuts global line-requests ~4x and makes them
// contiguous (the prior per-wave 16-line scatters were the MLP-limited invariant ~33us).
__global__ __launch_bounds__(256) void attn_k(
    const unsigned short* __restrict__ Qb, const unsigned short* __restrict__ Kb,
    const unsigned short* __restrict__ Vt, float* __restrict__ pO,
    float* __restrict__ pL)
{
    __shared__ __align__(16) unsigned short klds[2][64][64];
    __shared__ __align__(16) unsigned short vlds[2][64][64];
    const int tid = threadIdx.x;
    const int w = tid >> 6, lane = tid & 63;
    const int lrow = lane & 15, g = lane >> 4;
    const int bid = blockIdx.x;
    const int batch = bid >> 6;
    const int rem = bid & 63;
    const int pi = rem >> 2;
    const int j  = rem & 3;

    const unsigned short* Kbase = Kb + batch * 2048 * 64;
    const unsigned short* Vbase = Vt + batch * 131072;
    const float C2 = 0.03125f * 1.44269504088896f;      // E^-0.5 * log2(e)

    // staging map: thread -> (row sr, two 16B granules), swizzled LDS byte offsets
    const int sr = tid >> 2;
    const int sc32 = tid & 3;
    const int sb0 = sr * 128 + (((sc32 * 2)     ^ (sr & 7)) << 4);
    const int sb1 = sr * 128 + (((sc32 * 2 + 1) ^ (sr & 7)) << 4);

    // compute-side swizzle pieces
    const int swz = (lrow & 7) << 4;
    const int rb0 = (lrow) * 128, rb1 = (16 + lrow) * 128,
              rb2 = (32 + lrow) * 128, rb3 = (48 + lrow) * 128;
    const int gk0 = (g << 4) ^ swz;            // granule ks=0
    const int gk1 = ((4 + g) << 4) ^ swz;      // granule ks=1
    const bool odd = (g & 1);

#pragma unroll 1
    for (int phase = 0; phase < 2; ++phase) {
        const int B   = phase ? (31 - pi) : pi;
        const int qb  = B * 64;
        const int nch = B + 1;
        const int nc  = (nch > j) ? ((nch - j + 3) >> 2) : 0;

        const unsigned short* Qrow = Qb + (batch * 2048 + qb + w * 16 + lrow) * 64;
        bf16x8 q0 = *(const bf16x8*)(Qrow + g * 8);
        bf16x8 q1 = *(const bf16x8*)(Qrow + 32 + g * 8);
        const int qglob = qb + w * 16 + lrow;

        f32x4 o0 = {0.f,0.f,0.f,0.f}, o1 = o0, o2 = o0, o3 = o0;
        float lsum = 0.f;

        u16x8 rk0 = {}, rk1 = {}, rv0 = {}, rv1 = {};
        if (nc > 0) {                       // prologue: stage chunk j into buf0
            const int kvb = j * 64;
            const unsigned short* ksrc = Kbase + (kvb + sr) * 64 + sc32 * 16;
            rk0 = *(const u16x8*)(ksrc); rk1 = *(const u16x8*)(ksrc + 8);
            const unsigned short* vsrc = Vbase + sr * 2048 + kvb + sc32 * 16;
            rv0 = *(const u16x8*)(vsrc); rv1 = *(const u16x8*)(vsrc + 8);
            char* kb = (char*)&klds[0][0][0];
            char* vb = (char*)&vlds[0][0][0];
            *(u16x8*)(kb + sb0) = rk0; *(u16x8*)(kb + sb1) = rk1;
            *(u16x8*)(vb + sb0) = rv0; *(u16x8*)(vb + sb1) = rv1;
        }
        __syncthreads();

        for (int idx = 0; idx < nc; ++idx) {
            const int c = j + idx * 4;
            const int cur = idx & 1;
            const int kvbase = c * 64;
            if (idx + 1 < nc) {             // issue next chunk's global loads early
                const int kvb = kvbase + 256;
                const unsigned short* ksrc = Kbase + (kvb + sr) * 64 + sc32 * 16;
                rk0 = *(const u16x8*)(ksrc); rk1 = *(const u16x8*)(ksrc + 8);
                const unsigned short* vsrc = Vbase + sr * 2048 + kvb + sc32 * 16;
                rv0 = *(const u16x8*)(vsrc); rv1 = *(const u16x8*)(vsrc + 8);
            }

            const char* kb = (const char*)&klds[cur][0][0];
            const char* vb = (const char*)&vlds[cur][0][0];

            // QK^T (swapped): t_f[u] = S[kv = kvbase + f*16 + g*4+u][q = lrow]
            f32x4 t0 = {0.f,0.f,0.f,0.f}, t1 = t0, t2 = t0, t3 = t0;
            {
                bf16x8 a;
                a = *(const bf16x8*)(kb + rb0 + gk0); t0 = MFMA(a, q0, t0);
                a = *(const bf16x8*)(kb + rb0 + gk1); t0 = MFMA(a, q1, t0);
                a = *(const bf16x8*)(kb + rb1 + gk0); t1 = MFMA(a, q0, t1);
                a = *(const bf16x8*)(kb + rb1 + gk1); t1 = MFMA(a, q1, t1);
                a = *(const bf16x8*)(kb + rb2 + gk0); t2 = MFMA(a, q0, t2);
                a = *(const bf16x8*)(kb + rb2 + gk1); t2 = MFMA(a, q1, t2);
                a = *(const bf16x8*)(kb + rb3 + gk0); t3 = MFMA(a, q0, t3);
                a = *(const bf16x8*)(kb + rb3 + gk1); t3 = MFMA(a, q1, t3);
            }

            const bool maskc = (c == nch - 1);
            float eA[4], eB[4], eC[4], eD[4];
#pragma unroll
            for (int u = 0; u < 4; u++) {
                float v0 = t0[u] * C2, v1 = t1[u] * C2,
                      v2 = t2[u] * C2, v3 = t3[u] * C2;
                if (maskc) {
                    int kvr = kvbase + g * 4 + u;
                    v0 = (kvr      > qglob) ? -INFINITY : v0;
                    v1 = (kvr + 16 > qglob) ? -INFINITY : v1;
                    v2 = (kvr + 32 > qglob) ? -INFINITY : v2;
                    v3 = (kvr + 48 > qglob) ? -INFINITY : v3;
                }
                eA[u] = __builtin_exp2f(v0);
                eB[u] = __builtin_exp2f(v1);
                eC[u] = __builtin_exp2f(v2);
                eD[u] = __builtin_exp2f(v3);
                lsum += (eA[u] + eB[u]) + (eC[u] + eD[u]);
            }

            bf16x8 pa0 = pack_pa(eA[0],eA[1],eA[2],eA[3], eB[0],eB[1],eB[2],eB[3], odd);
            bf16x8 pa1 = pack_pa(eC[0],eC[1],eC[2],eC[3], eD[0],eD[1],eD[2],eD[3], odd);

            // PV: o_n += P * V  (V^T rows d = n*16+lrow)
            {
                bf16x8 vv;
                vv = *(const bf16x8*)(vb + rb0 + gk0); o0 = MFMA(pa0, vv, o0);
                vv = *(const bf16x8*)(vb + rb0 + gk1); o0 = MFMA(pa1, vv, o0);
                vv = *(const bf16x8*)(vb + rb1 + gk0); o1 = MFMA(pa0, vv, o1);
                vv = *(const bf16x8*)(vb + rb1 + gk1); o1 = MFMA(pa1, vv, o1);
                vv = *(const bf16x8*)(vb + rb2 + gk0); o2 = MFMA(pa0, vv, o2);
                vv = *(const bf16x8*)(vb + rb2 + gk1); o2 = MFMA(pa1, vv, o2);
                vv = *(const bf16x8*)(vb + rb3 + gk0); o3 = MFMA(pa0, vv, o3);
                vv = *(const bf16x8*)(vb + rb3 + gk1); o3 = MFMA(pa1, vv, o3);
            }

            __syncthreads();                 // all waves done reading buf[cur]
            if (idx + 1 < nc) {              // write next chunk into other buffer
                char* kw = (char*)&klds[cur ^ 1][0][0];
                char* vw = (char*)&vlds[cur ^ 1][0][0];
                *(u16x8*)(kw + sb0) = rk0; *(u16x8*)(kw + sb1) = rk1;
                *(u16x8*)(vw + sb0) = rv0; *(u16x8*)(vw + sb1) = rv1;
            }
            __syncthreads();                 // staged data visible
        }

        // write this quarter's partials (o-sum, l-sum); fixed-max => plain-additive
        const int qrow0 = batch * 2048 + qb + w * 16;
        float* po = pO + ((size_t)j * 16384 + qrow0) * 64;
#pragma unroll
        for (int u = 0; u < 4; u++) {
            int r = (g * 4 + u) * 64;
            po[r +      lrow] = o0[u];
            po[r + 16 + lrow] = o1[u];
            po[r + 32 + lrow] = o2[u];
            po[r + 48 + lrow] = o3[u];
        }
        lsum += __shfl_xor(lsum, 16);
        lsum += __shfl_xor(lsum, 32);
        if (lane < 16) pL[j * 16384 + qrow0 + lane] = lsum;
        __syncthreads();                     // LDS safe for next phase
    }
}

// ---------------- Kernel 3: merge the four kv-quarter partials ----------------
__global__ __launch_bounds__(256) void comb_k(
    const float* __restrict__ pO, const float* __restrict__ pL,
    float* __restrict__ out)
{
    const int J = 16384 * 64;
    int id = blockIdx.x * 256 + threadIdx.x;   // 65536 = 16384 rows x 4 quarters
    int row = id >> 2, q = (id & 3) * 16;
    float inv = 1.f / (pL[row] + pL[16384 + row] + pL[32768 + row] + pL[49152 + row]);
    const float* p0 = pO + row * 64 + q;
    float* op = out + row * 64 + q;
#pragma unroll
    for (int k = 0; k < 4; k++) {
        f32x4 s = *(const f32x4*)(p0 + 4 * k)
                + *(const f32x4*)(p0 + J + 4 * k)
                + *(const f32x4*)(p0 + 2 * J + 4 * k)
                + *(const f32x4*)(p0 + 3 * J + 4 * k);
        *(f32x4*)(op + 4 * k) = s * inv;
    }
}

extern "C" void kernel_launch(void* const* d_in, const int* in_sizes, int n_in,
                              void* d_out, int out_size, void* d_ws, size_t ws_size,
                              hipStream_t stream) {
    const float* x  = (const float*)d_in[0];
    const float* Wk = (const float*)d_in[1];
    const float* Wq = (const float*)d_in[2];
    const float* Wv = (const float*)d_in[3];
    float* out = (float*)d_out;

    unsigned short* Wt = (unsigned short*)d_ws;        // [192][1024] bf16
    unsigned short* Kb = Wt + 3 * 65536;               // [16384][64]
    unsigned short* Qb = Kb + 16384 * 64;              // [16384][64]
    unsigned short* Vt = Qb + 16384 * 64;              // [8][64][2048]
    float* pO = (float*)(Vt + 131072 * 8);             // [4][16384][64] f32 partial o
    float* pL = pO + 4 * 16384 * 64;                   // [4][16384] f32 partial l

    wtrans_k<<<48, 256, 0, stream>>>(Wk, Wq, Wv, Wt);
    qkv_k<<<512, 256, 0, stream>>>(x, Wt, Qb, Kb, Vt);
    attn_k<<<512, 256, 0, stream>>>(Qb, Kb, Vt, pO, pL);
    comb_k<<<256, 256, 0, stream>>>(pO, pL, out);
}

// Round 11
// 49.367 us; speedup vs baseline: 3.0820x; 1.0880x over previous
//
#include <hip/hip_runtime.h>

typedef __attribute__((ext_vector_type(8))) short bf16x8;
typedef __attribute__((ext_vector_type(4))) float f32x4;
typedef __attribute__((ext_vector_type(4))) unsigned short u16x4;
typedef __attribute__((ext_vector_type(8))) unsigned short u16x8;
typedef __attribute__((ext_vector_type(4))) unsigned int u32x4;

#define MFMA(a, b, c) __builtin_amdgcn_mfma_f32_16x16x32_bf16(a, b, c, 0, 0, 0)

static __device__ __forceinline__ unsigned short f2bf(float x) {
    union { float f; unsigned u; } v; v.f = x;
    unsigned r = v.u + 0x7fffu + ((v.u >> 16) & 1u);   // round-to-nearest-even
    return (unsigned short)(r >> 16);
}

// P-fragment pack (verified rounds 4-10).
static __device__ __forceinline__ bf16x8 pack_pa(
    float ea0, float ea1, float ea2, float ea3,
    float eb0, float eb1, float eb2, float eb3, bool odd)
{
    unsigned a1, a2, b1, b2;
    asm("v_cvt_pk_bf16_f32 %0, %1, %2" : "=v"(a1) : "v"(ea0), "v"(ea1));
    asm("v_cvt_pk_bf16_f32 %0, %1, %2" : "=v"(a2) : "v"(ea2), "v"(ea3));
    asm("v_cvt_pk_bf16_f32 %0, %1, %2" : "=v"(b1) : "v"(eb0), "v"(eb1));
    asm("v_cvt_pk_bf16_f32 %0, %1, %2" : "=v"(b2) : "v"(eb2), "v"(eb3));
    asm("v_permlane32_swap_b32 %0, %1" : "+v"(a1), "+v"(b1));
    asm("v_permlane32_swap_b32 %0, %1" : "+v"(a2), "+v"(b2));
    int sa1 = __shfl_xor((int)a1, 16);
    int sa2 = __shfl_xor((int)a2, 16);
    int sb1 = __shfl_xor((int)b1, 16);
    int sb2 = __shfl_xor((int)b2, 16);
    u32x4 paw;
    paw[0] = odd ? (unsigned)sb1 : a1;
    paw[1] = odd ? (unsigned)sb2 : a2;
    paw[2] = odd ? b1 : (unsigned)sa1;
    paw[3] = odd ? b2 : (unsigned)sa2;
    return __builtin_bit_cast(bf16x8, paw);
}

// ---------------- Kernel 0: W [1024][64] f32 -> Wt [3][64][1024] bf16 ----------------
__global__ __launch_bounds__(256) void wtrans_k(
    const float* __restrict__ Wk, const float* __restrict__ Wq,
    const float* __restrict__ Wv, unsigned short* __restrict__ Wt)
{
    __shared__ float tl[64][65];
    const int w = blockIdx.x >> 4, kt = blockIdx.x & 15;
    const float* W = (w == 0) ? Wk : (w == 1) ? Wq : Wv;
    const int tid = threadIdx.x;
#pragma unroll
    for (int rep = 0; rep < 4; rep++) {
        int flat = rep * 256 + tid;
        int rr = flat >> 4, c4 = (flat & 15) * 4;
        f32x4 v = *(const f32x4*)(W + (kt * 64 + rr) * 64 + c4);
#pragma unroll
        for (int jj = 0; jj < 4; jj++) tl[c4 + jj][rr] = v[jj];
    }
    __syncthreads();
#pragma unroll
    for (int rep = 0; rep < 2; rep++) {
        int flat = rep * 256 + tid;
        int n = flat >> 3, k8 = (flat & 7) * 8;
        u16x8 h;
#pragma unroll
        for (int jj = 0; jj < 8; jj++) h[jj] = f2bf(tl[n][k8 + jj]);
        *(u16x8*)(Wt + w * 65536 + n * 1024 + kt * 64 + k8) = h;
    }
}

// ---------------- Kernel 1: QKV projection v2 ----------------
// 256 blocks x 512 thr. M=64 rows/block (halves W L2 traffic vs M=32).
// Double-buffered LDS; register-staged prefetch: iter t = {write regs->buf, issue t+1
// loads, ONE barrier, MFMA} so HBM latency hides under MFMA and loads cross the barrier.
__global__ __launch_bounds__(512) void qkv_k(
    const float* __restrict__ x, const unsigned short* __restrict__ Wt,
    unsigned short* __restrict__ Qb, unsigned short* __restrict__ Kb,
    unsigned short* __restrict__ Vt)
{
    __shared__ __align__(16) unsigned short xl[2][64][72];   // +8 pad: 2-way max
    __shared__ __align__(16) unsigned short wl[2][192][72];
    const int tid = threadIdx.x;
    const int wid = tid >> 6, lane = tid & 63;
    const int lrow = lane & 15, g = lane >> 4;
    const int mbase = blockIdx.x * 64;
    const int msrow = (wid & 3) * 16;        // 4 m-subtiles
    const int ntbase = (wid >> 2) * 6;       // 2 n-groups of 6 tiles

    // staging maps
    const int xrow = tid >> 3, xc8 = (tid & 7) * 8;          // x: 8 f32/thread
    const int wrow = tid >> 3, wc8 = (tid & 7) * 8;          // W: 3 rows of 64 apart

    f32x4 acc[6];
#pragma unroll
    for (int j = 0; j < 6; j++) acc[j] = (f32x4){0.f, 0.f, 0.f, 0.f};

    // prologue: load chunk 0 into regs
    f32x4 vx0, vx1;
    u16x8 rw0, rw1, rw2;
    {
        const float* xs = x + (mbase + xrow) * 1024 + xc8;
        vx0 = *(const f32x4*)(xs);
        vx1 = *(const f32x4*)(xs + 4);
        const unsigned short* ws = Wt + wrow * 1024 + wc8;
        rw0 = *(const u16x8*)(ws);
        rw1 = *(const u16x8*)(ws + 64 * 1024);
        rw2 = *(const u16x8*)(ws + 128 * 1024);
    }

#pragma unroll 1
    for (int t = 0; t < 16; ++t) {
        const int buf = t & 1;
        // write staged regs -> LDS (cvt x to bf16 here)
        {
            unsigned d0, d1, d2, d3;
            asm("v_cvt_pk_bf16_f32 %0, %1, %2" : "=v"(d0) : "v"(vx0[0]), "v"(vx0[1]));
            asm("v_cvt_pk_bf16_f32 %0, %1, %2" : "=v"(d1) : "v"(vx0[2]), "v"(vx0[3]));
            asm("v_cvt_pk_bf16_f32 %0, %1, %2" : "=v"(d2) : "v"(vx1[0]), "v"(vx1[1]));
            asm("v_cvt_pk_bf16_f32 %0, %1, %2" : "=v"(d3) : "v"(vx1[2]), "v"(vx1[3]));
            u32x4 pk; pk[0] = d0; pk[1] = d1; pk[2] = d2; pk[3] = d3;
            *(u32x4*)&xl[buf][xrow][xc8] = pk;
            *(u16x8*)&wl[buf][wrow][wc8]       = rw0;
            *(u16x8*)&wl[buf][wrow + 64][wc8]  = rw1;
            *(u16x8*)&wl[buf][wrow + 128][wc8] = rw2;
        }
        // issue next chunk's global loads (in flight across the barrier, under MFMA)
        if (t < 15) {
            const int kc = (t + 1) * 64;
            const float* xs = x + (mbase + xrow) * 1024 + kc + xc8;
            vx0 = *(const f32x4*)(xs);
            vx1 = *(const f32x4*)(xs + 4);
            const unsigned short* ws = Wt + wrow * 1024 + kc + wc8;
            rw0 = *(const u16x8*)(ws);
            rw1 = *(const u16x8*)(ws + 64 * 1024);
            rw2 = *(const u16x8*)(ws + 128 * 1024);
        }
        __syncthreads();
#pragma unroll
        for (int ks = 0; ks < 2; ks++) {
            bf16x8 a = *(const bf16x8*)&xl[buf][msrow + lrow][ks * 32 + g * 8];
#pragma unroll
            for (int j = 0; j < 6; j++) {
                bf16x8 b = *(const bf16x8*)&wl[buf][(ntbase + j) * 16 + lrow][ks * 32 + g * 8];
                acc[j] = MFMA(a, b, acc[j]);
            }
        }
    }

#pragma unroll
    for (int j = 0; j < 6; j++) {
        int nt = ntbase + j;
        int w = nt >> 2;
        int col = (nt & 3) * 16 + lrow;
        int r0 = mbase + msrow + g * 4;
        if (w == 2) {
            int b = r0 >> 11, tt = r0 & 2047;
            u16x4 pv;
            pv[0] = f2bf(acc[j][0]); pv[1] = f2bf(acc[j][1]);
            pv[2] = f2bf(acc[j][2]); pv[3] = f2bf(acc[j][3]);
            *(u16x4*)(Vt + b * 131072 + col * 2048 + tt) = pv;
        } else {
            unsigned short* dst = (w == 0) ? Kb : Qb;
#pragma unroll
            for (int i = 0; i < 4; i++)
                dst[(r0 + i) * 64 + col] = f2bf(acc[j][i]);
        }
    }
}

// ---------------- Kernel 2: attention v10 (unchanged from round 10) ----------------
__global__ __launch_bounds__(256) void attn_k(
    const unsigned short* __restrict__ Qb, const unsigned short* __restrict__ Kb,
    const unsigned short* __restrict__ Vt, float* __restrict__ pO,
    float* __restrict__ pL)
{
    __shared__ __align__(16) unsigned short klds[2][64][64];
    __shared__ __align__(16) unsigned short vlds[2][64][64];
    const int tid = threadIdx.x;
    const int w = tid >> 6, lane = tid & 63;
    const int lrow = lane & 15, g = lane >> 4;
    const int bid = blockIdx.x;
    const int batch = bid >> 6;
    const int rem = bid & 63;
    const int pi = rem >> 2;
    const int j  = rem & 3;

    const unsigned short* Kbase = Kb + batch * 2048 * 64;
    const unsigned short* Vbase = Vt + batch * 131072;
    const float C2 = 0.03125f * 1.44269504088896f;      // E^-0.5 * log2(e)

    const int sr = tid >> 2;
    const int sc32 = tid & 3;
    const int sb0 = sr * 128 + (((sc32 * 2)     ^ (sr & 7)) << 4);
    const int sb1 = sr * 128 + (((sc32 * 2 + 1) ^ (sr & 7)) << 4);

    const int swz = (lrow & 7) << 4;
    const int rb0 = (lrow) * 128, rb1 = (16 + lrow) * 128,
              rb2 = (32 + lrow) * 128, rb3 = (48 + lrow) * 128;
    const int gk0 = (g << 4) ^ swz;
    const int gk1 = ((4 + g) << 4) ^ swz;
    const bool odd = (g & 1);

#pragma unroll 1
    for (int phase = 0; phase < 2; ++phase) {
        const int B   = phase ? (31 - pi) : pi;
        const int qb  = B * 64;
        const int nch = B + 1;
        const int nc  = (nch > j) ? ((nch - j + 3) >> 2) : 0;

        const unsigned short* Qrow = Qb + (batch * 2048 + qb + w * 16 + lrow) * 64;
        bf16x8 q0 = *(const bf16x8*)(Qrow + g * 8);
        bf16x8 q1 = *(const bf16x8*)(Qrow + 32 + g * 8);
        const int qglob = qb + w * 16 + lrow;

        f32x4 o0 = {0.f,0.f,0.f,0.f}, o1 = o0, o2 = o0, o3 = o0;
        float lsum = 0.f;

        u16x8 rk0 = {}, rk1 = {}, rv0 = {}, rv1 = {};
        if (nc > 0) {
            const int kvb = j * 64;
            const unsigned short* ksrc = Kbase + (kvb + sr) * 64 + sc32 * 16;
            rk0 = *(const u16x8*)(ksrc); rk1 = *(const u16x8*)(ksrc + 8);
            const unsigned short* vsrc = Vbase + sr * 2048 + kvb + sc32 * 16;
            rv0 = *(const u16x8*)(vsrc); rv1 = *(const u16x8*)(vsrc + 8);
            char* kb = (char*)&klds[0][0][0];
            char* vb = (char*)&vlds[0][0][0];
            *(u16x8*)(kb + sb0) = rk0; *(u16x8*)(kb + sb1) = rk1;
            *(u16x8*)(vb + sb0) = rv0; *(u16x8*)(vb + sb1) = rv1;
        }
        __syncthreads();

        for (int idx = 0; idx < nc; ++idx) {
            const int c = j + idx * 4;
            const int cur = idx & 1;
            const int kvbase = c * 64;
            if (idx + 1 < nc) {
                const int kvb = kvbase + 256;
                const unsigned short* ksrc = Kbase + (kvb + sr) * 64 + sc32 * 16;
                rk0 = *(const u16x8*)(ksrc); rk1 = *(const u16x8*)(ksrc + 8);
                const unsigned short* vsrc = Vbase + sr * 2048 + kvb + sc32 * 16;
                rv0 = *(const u16x8*)(vsrc); rv1 = *(const u16x8*)(vsrc + 8);
            }

            const char* kb = (const char*)&klds[cur][0][0];
            const char* vb = (const char*)&vlds[cur][0][0];

            f32x4 t0 = {0.f,0.f,0.f,0.f}, t1 = t0, t2 = t0, t3 = t0;
            {
                bf16x8 a;
                a = *(const bf16x8*)(kb + rb0 + gk0); t0 = MFMA(a, q0, t0);
                a = *(const bf16x8*)(kb + rb0 + gk1); t0 = MFMA(a, q1, t0);
                a = *(const bf16x8*)(kb + rb1 + gk0); t1 = MFMA(a, q0, t1);
                a = *(const bf16x8*)(kb + rb1 + gk1); t1 = MFMA(a, q1, t1);
                a = *(const bf16x8*)(kb + rb2 + gk0); t2 = MFMA(a, q0, t2);
                a = *(const bf16x8*)(kb + rb2 + gk1); t2 = MFMA(a, q1, t2);
                a = *(const bf16x8*)(kb + rb3 + gk0); t3 = MFMA(a, q0, t3);
                a = *(const bf16x8*)(kb + rb3 + gk1); t3 = MFMA(a, q1, t3);
            }

            const bool maskc = (c == nch - 1);
            float eA[4], eB[4], eC[4], eD[4];
#pragma unroll
            for (int u = 0; u < 4; u++) {
                float v0 = t0[u] * C2, v1 = t1[u] * C2,
                      v2 = t2[u] * C2, v3 = t3[u] * C2;
                if (maskc) {
                    int kvr = kvbase + g * 4 + u;
                    v0 = (kvr      > qglob) ? -INFINITY : v0;
                    v1 = (kvr + 16 > qglob) ? -INFINITY : v1;
                    v2 = (kvr + 32 > qglob) ? -INFINITY : v2;
                    v3 = (kvr + 48 > qglob) ? -INFINITY : v3;
                }
                eA[u] = __builtin_exp2f(v0);
                eB[u] = __builtin_exp2f(v1);
                eC[u] = __builtin_exp2f(v2);
                eD[u] = __builtin_exp2f(v3);
                lsum += (eA[u] + eB[u]) + (eC[u] + eD[u]);
            }

            bf16x8 pa0 = pack_pa(eA[0],eA[1],eA[2],eA[3], eB[0],eB[1],eB[2],eB[3], odd);
            bf16x8 pa1 = pack_pa(eC[0],eC[1],eC[2],eC[3], eD[0],eD[1],eD[2],eD[3], odd);

            {
                bf16x8 vv;
                vv = *(const bf16x8*)(vb + rb0 + gk0); o0 = MFMA(pa0, vv, o0);
                vv = *(const bf16x8*)(vb + rb0 + gk1); o0 = MFMA(pa1, vv, o0);
                vv = *(const bf16x8*)(vb + rb1 + gk0); o1 = MFMA(pa0, vv, o1);
                vv = *(const bf16x8*)(vb + rb1 + gk1); o1 = MFMA(pa1, vv, o1);
                vv = *(const bf16x8*)(vb + rb2 + gk0); o2 = MFMA(pa0, vv, o2);
                vv = *(const bf16x8*)(vb + rb2 + gk1); o2 = MFMA(pa1, vv, o2);
                vv = *(const bf16x8*)(vb + rb3 + gk0); o3 = MFMA(pa0, vv, o3);
                vv = *(const bf16x8*)(vb + rb3 + gk1); o3 = MFMA(pa1, vv, o3);
            }

            __syncthreads();
            if (idx + 1 < nc) {
                char* kw = (char*)&klds[cur ^ 1][0][0];
                char* vw = (char*)&vlds[cur ^ 1][0][0];
                *(u16x8*)(kw + sb0) = rk0; *(u16x8*)(kw + sb1) = rk1;
                *(u16x8*)(vw + sb0) = rv0; *(u16x8*)(vw + sb1) = rv1;
            }
            __syncthreads();
        }

        const int qrow0 = batch * 2048 + qb + w * 16;
        float* po = pO + ((size_t)j * 16384 + qrow0) * 64;
#pragma unroll
        for (int u = 0; u < 4; u++) {
            int r = (g * 4 + u) * 64;
            po[r +      lrow] = o0[u];
            po[r + 16 + lrow] = o1[u];
            po[r + 32 + lrow] = o2[u];
            po[r + 48 + lrow] = o3[u];
        }
        lsum += __shfl_xor(lsum, 16);
        lsum += __shfl_xor(lsum, 32);
        if (lane < 16) pL[j * 16384 + qrow0 + lane] = lsum;
        __syncthreads();
    }
}

// ---------------- Kernel 3: merge the four kv-quarter partials ----------------
__global__ __launch_bounds__(256) void comb_k(
    const float* __restrict__ pO, const float* __restrict__ pL,
    float* __restrict__ out)
{
    const int J = 16384 * 64;
    int id = blockIdx.x * 256 + threadIdx.x;
    int row = id >> 2, q = (id & 3) * 16;
    float inv = 1.f / (pL[row] + pL[16384 + row] + pL[32768 + row] + pL[49152 + row]);
    const float* p0 = pO + row * 64 + q;
    float* op = out + row * 64 + q;
#pragma unroll
    for (int k = 0; k < 4; k++) {
        f32x4 s = *(const f32x4*)(p0 + 4 * k)
                + *(const f32x4*)(p0 + J + 4 * k)
                + *(const f32x4*)(p0 + 2 * J + 4 * k)
                + *(const f32x4*)(p0 + 3 * J + 4 * k);
        *(f32x4*)(op + 4 * k) = s * inv;
    }
}

extern "C" void kernel_launch(void* const* d_in, const int* in_sizes, int n_in,
                              void* d_out, int out_size, void* d_ws, size_t ws_size,
                              hipStream_t stream) {
    const float* x  = (const float*)d_in[0];
    const float* Wk = (const float*)d_in[1];
    const float* Wq = (const float*)d_in[2];
    const float* Wv = (const float*)d_in[3];
    float* out = (float*)d_out;

    unsigned short* Wt = (unsigned short*)d_ws;        // [192][1024] bf16
    unsigned short* Kb = Wt + 3 * 65536;               // [16384][64]
    unsigned short* Qb = Kb + 16384 * 64;              // [16384][64]
    unsigned short* Vt = Qb + 16384 * 64;              // [8][64][2048]
    float* pO = (float*)(Vt + 131072 * 8);             // [4][16384][64] f32 partial o
    float* pL = pO + 4 * 16384 * 64;                   // [4][16384] f32 partial l

    wtrans_k<<<48, 256, 0, stream>>>(Wk, Wq, Wv, Wt);
    qkv_k<<<256, 512, 0, stream>>>(x, Wt, Qb, Kb, Vt);
    attn_k<<<512, 256, 0, stream>>>(Qb, Kb, Vt, pO, pL);
    comb_k<<<256, 256, 0, stream>>>(pO, pL, out);
}

// Round 12
// 48.422 us; speedup vs baseline: 3.1421x; 1.0195x over previous
//
#include <hip/hip_runtime.h>

typedef __attribute__((ext_vector_type(8))) short bf16x8;
typedef __attribute__((ext_vector_type(4))) float f32x4;
typedef __attribute__((ext_vector_type(4))) unsigned short u16x4;
typedef __attribute__((ext_vector_type(8))) unsigned short u16x8;
typedef __attribute__((ext_vector_type(4))) unsigned int u32x4;

#define MFMA(a, b, c) __builtin_amdgcn_mfma_f32_16x16x32_bf16(a, b, c, 0, 0, 0)

static __device__ __forceinline__ unsigned short f2bf(float x) {
    union { float f; unsigned u; } v; v.f = x;
    unsigned r = v.u + 0x7fffu + ((v.u >> 16) & 1u);   // round-to-nearest-even
    return (unsigned short)(r >> 16);
}

// P-fragment pack (verified rounds 4-11).
static __device__ __forceinline__ bf16x8 pack_pa(
    float ea0, float ea1, float ea2, float ea3,
    float eb0, float eb1, float eb2, float eb3, bool odd)
{
    unsigned a1, a2, b1, b2;
    asm("v_cvt_pk_bf16_f32 %0, %1, %2" : "=v"(a1) : "v"(ea0), "v"(ea1));
    asm("v_cvt_pk_bf16_f32 %0, %1, %2" : "=v"(a2) : "v"(ea2), "v"(ea3));
    asm("v_cvt_pk_bf16_f32 %0, %1, %2" : "=v"(b1) : "v"(eb0), "v"(eb1));
    asm("v_cvt_pk_bf16_f32 %0, %1, %2" : "=v"(b2) : "v"(eb2), "v"(eb3));
    asm("v_permlane32_swap_b32 %0, %1" : "+v"(a1), "+v"(b1));
    asm("v_permlane32_swap_b32 %0, %1" : "+v"(a2), "+v"(b2));
    int sa1 = __shfl_xor((int)a1, 16);
    int sa2 = __shfl_xor((int)a2, 16);
    int sb1 = __shfl_xor((int)b1, 16);
    int sb2 = __shfl_xor((int)b2, 16);
    u32x4 paw;
    paw[0] = odd ? (unsigned)sb1 : a1;
    paw[1] = odd ? (unsigned)sb2 : a2;
    paw[2] = odd ? b1 : (unsigned)sa1;
    paw[3] = odd ? b2 : (unsigned)sa2;
    return __builtin_bit_cast(bf16x8, paw);
}

// ---------------- Kernel 0: W [1024][64] f32 -> Wt [3][64][1024] bf16 ----------------
__global__ __launch_bounds__(256) void wtrans_k(
    const float* __restrict__ Wk, const float* __restrict__ Wq,
    const float* __restrict__ Wv, unsigned short* __restrict__ Wt)
{
    __shared__ float tl[64][65];
    const int w = blockIdx.x >> 4, kt = blockIdx.x & 15;
    const float* W = (w == 0) ? Wk : (w == 1) ? Wq : Wv;
    const int tid = threadIdx.x;
#pragma unroll
    for (int rep = 0; rep < 4; rep++) {
        int flat = rep * 256 + tid;
        int rr = flat >> 4, c4 = (flat & 15) * 4;
        f32x4 v = *(const f32x4*)(W + (kt * 64 + rr) * 64 + c4);
#pragma unroll
        for (int jj = 0; jj < 4; jj++) tl[c4 + jj][rr] = v[jj];
    }
    __syncthreads();
#pragma unroll
    for (int rep = 0; rep < 2; rep++) {
        int flat = rep * 256 + tid;
        int n = flat >> 3, k8 = (flat & 7) * 8;
        u16x8 h;
#pragma unroll
        for (int jj = 0; jj < 8; jj++) h[jj] = f2bf(tl[n][k8 + jj]);
        *(u16x8*)(Wt + w * 65536 + n * 1024 + kt * 64 + k8) = h;
    }
}

// ---------------- Kernel 1: QKV projection v3 ----------------
// 512 blocks x 256 thr, M=32 -> 2 blocks/CU (LDS 64.5KB). Same single-barrier
// register-prefetch pipeline as v2; two co-resident blocks fill each other's
// barrier-drain gaps so the x HBM stream stays saturated.
__global__ __launch_bounds__(256) void qkv_k(
    const float* __restrict__ x, const unsigned short* __restrict__ Wt,
    unsigned short* __restrict__ Qb, unsigned short* __restrict__ Kb,
    unsigned short* __restrict__ Vt)
{
    __shared__ __align__(16) unsigned short xl[2][32][72];   // +8 pad: 2-way max
    __shared__ __align__(16) unsigned short wl[2][192][72];
    const int tid = threadIdx.x;
    const int wid = tid >> 6, lane = tid & 63;
    const int lrow = lane & 15, g = lane >> 4;
    const int mbase = blockIdx.x * 32;
    const int msrow = (wid & 1) * 16;        // 2 m-subtiles
    const int ntbase = (wid >> 1) * 6;       // 2 n-groups of 6 tiles

    const int srow = tid >> 3, c8 = (tid & 7) * 8;  // staging map (both x and W)

    f32x4 acc[6];
#pragma unroll
    for (int j = 0; j < 6; j++) acc[j] = (f32x4){0.f, 0.f, 0.f, 0.f};

    // prologue: chunk 0 into regs
    f32x4 vx0, vx1;
    u16x8 rw0, rw1, rw2, rw3, rw4, rw5;
    {
        const float* xs = x + (mbase + srow) * 1024 + c8;
        vx0 = *(const f32x4*)(xs);
        vx1 = *(const f32x4*)(xs + 4);
        const unsigned short* ws = Wt + srow * 1024 + c8;
        rw0 = *(const u16x8*)(ws);
        rw1 = *(const u16x8*)(ws + 32 * 1024);
        rw2 = *(const u16x8*)(ws + 64 * 1024);
        rw3 = *(const u16x8*)(ws + 96 * 1024);
        rw4 = *(const u16x8*)(ws + 128 * 1024);
        rw5 = *(const u16x8*)(ws + 160 * 1024);
    }

#pragma unroll 1
    for (int t = 0; t < 16; ++t) {
        const int buf = t & 1;
        {
            unsigned d0, d1, d2, d3;
            asm("v_cvt_pk_bf16_f32 %0, %1, %2" : "=v"(d0) : "v"(vx0[0]), "v"(vx0[1]));
            asm("v_cvt_pk_bf16_f32 %0, %1, %2" : "=v"(d1) : "v"(vx0[2]), "v"(vx0[3]));
            asm("v_cvt_pk_bf16_f32 %0, %1, %2" : "=v"(d2) : "v"(vx1[0]), "v"(vx1[1]));
            asm("v_cvt_pk_bf16_f32 %0, %1, %2" : "=v"(d3) : "v"(vx1[2]), "v"(vx1[3]));
            u32x4 pk; pk[0] = d0; pk[1] = d1; pk[2] = d2; pk[3] = d3;
            *(u32x4*)&xl[buf][srow][c8] = pk;
            *(u16x8*)&wl[buf][srow][c8]        = rw0;
            *(u16x8*)&wl[buf][srow + 32][c8]   = rw1;
            *(u16x8*)&wl[buf][srow + 64][c8]   = rw2;
            *(u16x8*)&wl[buf][srow + 96][c8]   = rw3;
            *(u16x8*)&wl[buf][srow + 128][c8]  = rw4;
            *(u16x8*)&wl[buf][srow + 160][c8]  = rw5;
        }
        if (t < 15) {                        // next chunk's loads, in flight across barrier
            const int kc = (t + 1) * 64;
            const float* xs = x + (mbase + srow) * 1024 + kc + c8;
            vx0 = *(const f32x4*)(xs);
            vx1 = *(const f32x4*)(xs + 4);
            const unsigned short* ws = Wt + srow * 1024 + kc + c8;
            rw0 = *(const u16x8*)(ws);
            rw1 = *(const u16x8*)(ws + 32 * 1024);
            rw2 = *(const u16x8*)(ws + 64 * 1024);
            rw3 = *(const u16x8*)(ws + 96 * 1024);
            rw4 = *(const u16x8*)(ws + 128 * 1024);
            rw5 = *(const u16x8*)(ws + 160 * 1024);
        }
        __syncthreads();
#pragma unroll
        for (int ks = 0; ks < 2; ks++) {
            bf16x8 a = *(const bf16x8*)&xl[buf][msrow + lrow][ks * 32 + g * 8];
#pragma unroll
            for (int j = 0; j < 6; j++) {
                bf16x8 b = *(const bf16x8*)&wl[buf][(ntbase + j) * 16 + lrow][ks * 32 + g * 8];
                acc[j] = MFMA(a, b, acc[j]);
            }
        }
    }

#pragma unroll
    for (int j = 0; j < 6; j++) {
        int nt = ntbase + j;
        int w = nt >> 2;
        int col = (nt & 3) * 16 + lrow;
        int r0 = mbase + msrow + g * 4;
        if (w == 2) {
            int b = r0 >> 11, tt = r0 & 2047;
            u16x4 pv;
            pv[0] = f2bf(acc[j][0]); pv[1] = f2bf(acc[j][1]);
            pv[2] = f2bf(acc[j][2]); pv[3] = f2bf(acc[j][3]);
            *(u16x4*)(Vt + b * 131072 + col * 2048 + tt) = pv;
        } else {
            unsigned short* dst = (w == 0) ? Kb : Qb;
#pragma unroll
            for (int i = 0; i < 4; i++)
                dst[(r0 + i) * 64 + col] = f2bf(acc[j][i]);
        }
    }
}

// ---------------- Kernel 2: attention v12 — one band per block, 4 blocks/CU ----------------
// 1024 blocks = band(32) x batch(8) x quarter(4); all co-resident (LDS 32KB -> 4/CU).
// Band mapping B = idx<16 ? 31-idx : idx-16 gives each CU a constant ~66-chunk load.
// Body (staging, QK-swap, pack, PV, partials) identical to verified rounds 10-11.
__global__ __launch_bounds__(256) void attn_k(
    const unsigned short* __restrict__ Qb, const unsigned short* __restrict__ Kb,
    const unsigned short* __restrict__ Vt, float* __restrict__ pO,
    float* __restrict__ pL)
{
    __shared__ __align__(16) unsigned short klds[2][64][64];
    __shared__ __align__(16) unsigned short vlds[2][64][64];
    const int tid = threadIdx.x;
    const int w = tid >> 6, lane = tid & 63;
    const int lrow = lane & 15, g = lane >> 4;
    const int bid = blockIdx.x;
    const int bandIdx = bid >> 5;
    const int batch = (bid >> 2) & 7;
    const int j = bid & 3;
    const int B = (bandIdx < 16) ? (31 - bandIdx) : (bandIdx - 16);

    const int qb  = B * 64;
    const int nch = B + 1;
    const int nc  = (nch > j) ? ((nch - j + 3) >> 2) : 0;

    const unsigned short* Kbase = Kb + batch * 2048 * 64;
    const unsigned short* Vbase = Vt + batch * 131072;
    const float C2 = 0.03125f * 1.44269504088896f;      // E^-0.5 * log2(e)

    const int sr = tid >> 2;
    const int sc32 = tid & 3;
    const int sb0 = sr * 128 + (((sc32 * 2)     ^ (sr & 7)) << 4);
    const int sb1 = sr * 128 + (((sc32 * 2 + 1) ^ (sr & 7)) << 4);

    const int swz = (lrow & 7) << 4;
    const int rb0 = (lrow) * 128, rb1 = (16 + lrow) * 128,
              rb2 = (32 + lrow) * 128, rb3 = (48 + lrow) * 128;
    const int gk0 = (g << 4) ^ swz;
    const int gk1 = ((4 + g) << 4) ^ swz;
    const bool odd = (g & 1);

    const unsigned short* Qrow = Qb + (batch * 2048 + qb + w * 16 + lrow) * 64;
    bf16x8 q0 = *(const bf16x8*)(Qrow + g * 8);
    bf16x8 q1 = *(const bf16x8*)(Qrow + 32 + g * 8);
    const int qglob = qb + w * 16 + lrow;

    f32x4 o0 = {0.f,0.f,0.f,0.f}, o1 = o0, o2 = o0, o3 = o0;
    float lsum = 0.f;

    u16x8 rk0 = {}, rk1 = {}, rv0 = {}, rv1 = {};
    if (nc > 0) {                            // prologue: stage chunk j into buf0
        const int kvb = j * 64;
        const unsigned short* ksrc = Kbase + (kvb + sr) * 64 + sc32 * 16;
        rk0 = *(const u16x8*)(ksrc); rk1 = *(const u16x8*)(ksrc + 8);
        const unsigned short* vsrc = Vbase + sr * 2048 + kvb + sc32 * 16;
        rv0 = *(const u16x8*)(vsrc); rv1 = *(const u16x8*)(vsrc + 8);
        char* kb = (char*)&klds[0][0][0];
        char* vb = (char*)&vlds[0][0][0];
        *(u16x8*)(kb + sb0) = rk0; *(u16x8*)(kb + sb1) = rk1;
        *(u16x8*)(vb + sb0) = rv0; *(u16x8*)(vb + sb1) = rv1;
    }
    __syncthreads();

    for (int idx = 0; idx < nc; ++idx) {
        const int c = j + idx * 4;
        const int cur = idx & 1;
        const int kvbase = c * 64;
        if (idx + 1 < nc) {                  // next chunk's loads, early
            const int kvb = kvbase + 256;
            const unsigned short* ksrc = Kbase + (kvb + sr) * 64 + sc32 * 16;
            rk0 = *(const u16x8*)(ksrc); rk1 = *(const u16x8*)(ksrc + 8);
            const unsigned short* vsrc = Vbase + sr * 2048 + kvb + sc32 * 16;
            rv0 = *(const u16x8*)(vsrc); rv1 = *(const u16x8*)(vsrc + 8);
        }

        const char* kb = (const char*)&klds[cur][0][0];
        const char* vb = (const char*)&vlds[cur][0][0];

        f32x4 t0 = {0.f,0.f,0.f,0.f}, t1 = t0, t2 = t0, t3 = t0;
        {
            bf16x8 a;
            a = *(const bf16x8*)(kb + rb0 + gk0); t0 = MFMA(a, q0, t0);
            a = *(const bf16x8*)(kb + rb0 + gk1); t0 = MFMA(a, q1, t0);
            a = *(const bf16x8*)(kb + rb1 + gk0); t1 = MFMA(a, q0, t1);
            a = *(const bf16x8*)(kb + rb1 + gk1); t1 = MFMA(a, q1, t1);
            a = *(const bf16x8*)(kb + rb2 + gk0); t2 = MFMA(a, q0, t2);
            a = *(const bf16x8*)(kb + rb2 + gk1); t2 = MFMA(a, q1, t2);
            a = *(const bf16x8*)(kb + rb3 + gk0); t3 = MFMA(a, q0, t3);
            a = *(const bf16x8*)(kb + rb3 + gk1); t3 = MFMA(a, q1, t3);
        }

        const bool maskc = (c == nch - 1);
        float eA[4], eB[4], eC[4], eD[4];
#pragma unroll
        for (int u = 0; u < 4; u++) {
            float v0 = t0[u] * C2, v1 = t1[u] * C2,
                  v2 = t2[u] * C2, v3 = t3[u] * C2;
            if (maskc) {
                int kvr = kvbase + g * 4 + u;
                v0 = (kvr      > qglob) ? -INFINITY : v0;
                v1 = (kvr + 16 > qglob) ? -INFINITY : v1;
                v2 = (kvr + 32 > qglob) ? -INFINITY : v2;
                v3 = (kvr + 48 > qglob) ? -INFINITY : v3;
            }
            eA[u] = __builtin_exp2f(v0);
            eB[u] = __builtin_exp2f(v1);
            eC[u] = __builtin_exp2f(v2);
            eD[u] = __builtin_exp2f(v3);
            lsum += (eA[u] + eB[u]) + (eC[u] + eD[u]);
        }

        bf16x8 pa0 = pack_pa(eA[0],eA[1],eA[2],eA[3], eB[0],eB[1],eB[2],eB[3], odd);
        bf16x8 pa1 = pack_pa(eC[0],eC[1],eC[2],eC[3], eD[0],eD[1],eD[2],eD[3], odd);

        {
            bf16x8 vv;
            vv = *(const bf16x8*)(vb + rb0 + gk0); o0 = MFMA(pa0, vv, o0);
            vv = *(const bf16x8*)(vb + rb0 + gk1); o0 = MFMA(pa1, vv, o0);
            vv = *(const bf16x8*)(vb + rb1 + gk0); o1 = MFMA(pa0, vv, o1);
            vv = *(const bf16x8*)(vb + rb1 + gk1); o1 = MFMA(pa1, vv, o1);
            vv = *(const bf16x8*)(vb + rb2 + gk0); o2 = MFMA(pa0, vv, o2);
            vv = *(const bf16x8*)(vb + rb2 + gk1); o2 = MFMA(pa1, vv, o2);
            vv = *(const bf16x8*)(vb + rb3 + gk0); o3 = MFMA(pa0, vv, o3);
            vv = *(const bf16x8*)(vb + rb3 + gk1); o3 = MFMA(pa1, vv, o3);
        }

        __syncthreads();                     // all waves done reading buf[cur]
        if (idx + 1 < nc) {
            char* kw = (char*)&klds[cur ^ 1][0][0];
            char* vw = (char*)&vlds[cur ^ 1][0][0];
            *(u16x8*)(kw + sb0) = rk0; *(u16x8*)(kw + sb1) = rk1;
            *(u16x8*)(vw + sb0) = rv0; *(u16x8*)(vw + sb1) = rv1;
        }
        __syncthreads();                     // staged data visible
    }

    // write this quarter's partials (zeros if nc==0 — comb_k sums all four)
    const int qrow0 = batch * 2048 + qb + w * 16;
    float* po = pO + ((size_t)j * 16384 + qrow0) * 64;
#pragma unroll
    for (int u = 0; u < 4; u++) {
        int r = (g * 4 + u) * 64;
        po[r +      lrow] = o0[u];
        po[r + 16 + lrow] = o1[u];
        po[r + 32 + lrow] = o2[u];
        po[r + 48 + lrow] = o3[u];
    }
    lsum += __shfl_xor(lsum, 16);
    lsum += __shfl_xor(lsum, 32);
    if (lane < 16) pL[j * 16384 + qrow0 + lane] = lsum;
}

// ---------------- Kernel 3: merge the four kv-quarter partials ----------------
__global__ __launch_bounds__(256) void comb_k(
    const float* __restrict__ pO, const float* __restrict__ pL,
    float* __restrict__ out)
{
    const int J = 16384 * 64;
    int id = blockIdx.x * 256 + threadIdx.x;
    int row = id >> 2, q = (id & 3) * 16;
    float inv = 1.f / (pL[row] + pL[16384 + row] + pL[32768 + row] + pL[49152 + row]);
    const float* p0 = pO + row * 64 + q;
    float* op = out + row * 64 + q;
#pragma unroll
    for (int k = 0; k < 4; k++) {
        f32x4 s = *(const f32x4*)(p0 + 4 * k)
                + *(const f32x4*)(p0 + J + 4 * k)
                + *(const f32x4*)(p0 + 2 * J + 4 * k)
                + *(const f32x4*)(p0 + 3 * J + 4 * k);
        *(f32x4*)(op + 4 * k) = s * inv;
    }
}

extern "C" void kernel_launch(void* const* d_in, const int* in_sizes, int n_in,
                              void* d_out, int out_size, void* d_ws, size_t ws_size,
                              hipStream_t stream) {
    const float* x  = (const float*)d_in[0];
    const float* Wk = (const float*)d_in[1];
    const float* Wq = (const float*)d_in[2];
    const float* Wv = (const float*)d_in[3];
    float* out = (float*)d_out;

    unsigned short* Wt = (unsigned short*)d_ws;        // [192][1024] bf16
    unsigned short* Kb = Wt + 3 * 65536;               // [16384][64]
    unsigned short* Qb = Kb + 16384 * 64;              // [16384][64]
    unsigned short* Vt = Qb + 16384 * 64;              // [8][64][2048]
    float* pO = (float*)(Vt + 131072 * 8);             // [4][16384][64] f32 partial o
    float* pL = pO + 4 * 16384 * 64;                   // [4][16384] f32 partial l

    wtrans_k<<<48, 256, 0, stream>>>(Wk, Wq, Wv, Wt);
    qkv_k<<<512, 256, 0, stream>>>(x, Wt, Qb, Kb, Vt);
    attn_k<<<1024, 256, 0, stream>>>(Qb, Kb, Vt, pO, pL);
    comb_k<<<256, 256, 0, stream>>>(pO, pL, out);
}